// Round 10
// baseline (401.099 us; speedup 1.0000x reference)
//
#include <hip/hip_runtime.h>

#define N_NODES 50000
#define M_PAD 50048            // 391 * 128
#define MT 391
#define F_IN 256
#define F_H 128
#define F_OUT 64
#define E_MAX 1600000
#define NEG_SLOPE 0.2f
#define EPS_F 1e-16f
#define NPART 196              // ceil(50000/256)
#define NBUCK 196              // coarse buckets: dst >> 8
#define CH_E 4096              // edges per sortA block -> 391 blocks
#define NQUAD 12500            // N_NODES / 4
#define ATT_GRID 2048          // persistent blocks
#define FUSED_LDS 61440        // gemm1 60KB (A 2x10KB + B 2x20KB) >= sortA 24KB

typedef __bf16 bf16x8 __attribute__((ext_vector_type(8)));
typedef float f32x4 __attribute__((ext_vector_type(4)));
typedef float f32x2 __attribute__((ext_vector_type(2)));

// ---------------- device-global scratch ------------------------------------
__device__ unsigned short g_B1h[256 * 256];
__device__ unsigned short g_B1l[256 * 256];
__device__ unsigned short g_B2h[128 * 128];
__device__ unsigned short g_B2l[128 * 128];
__device__ unsigned short g_hh[(size_t)M_PAD * F_H];
__device__ unsigned short g_hl[(size_t)M_PAD * F_H];
// gather tables: xl in bf16 (halves gather bytes), xr in f32 (read once/dst)
__device__ unsigned short g_xl1b[(size_t)N_NODES * F_H];
__device__ float g_xr1[(size_t)N_NODES * F_H];
__device__ unsigned short g_xl2b[(size_t)N_NODES * F_OUT];
__device__ float g_xr2[(size_t)N_NODES * F_OUT];
// CSR by dst
__device__ unsigned g_cnt[N_NODES];        // zero at load; self-zeroed by scanC2
__device__ unsigned g_part[NPART];
__device__ unsigned g_rowstart[N_NODES + 1];
__device__ unsigned g_bcursor[NBUCK];
__device__ unsigned g_bucketed[E_MAX];     // packed src | dst<<16
__device__ int g_src_sorted[E_MAX];

// ---------------- helpers ---------------------------------------------------
__device__ inline float san(float v) { return fminf(fmaxf(v, -64.f), 64.f); }
__device__ inline unsigned short f2bf(float f) {        // RNE f32->bf16
    unsigned u = __float_as_uint(f);
    return (unsigned short)((u + 0x7fffu + ((u >> 16) & 1u)) >> 16);
}
__device__ inline float bf2f(unsigned short h) {
    return __uint_as_float(((unsigned)h) << 16);
}
__device__ inline float blo(unsigned w) { return __uint_as_float(w << 16); }
__device__ inline float bhi(unsigned w) { return __uint_as_float(w & 0xffff0000u); }

// ---------------- fused prep: weight prepack + pad_h + csr_hist -------------
__global__ __launch_bounds__(256) void prep_hist(const int* __restrict__ dst, int E,
                                                 const float* __restrict__ Wl1,
                                                 const float* __restrict__ Wr1,
                                                 const float* __restrict__ Wl2,
                                                 const float* __restrict__ Wr2) {
    int i = blockIdx.x * 256 + threadIdx.x;
    if (i < 256 * 256) {                               // W1 prepack
        int n = i >> 8, k = i & 255;
        float v = san((n < 128) ? Wl1[k * 128 + n] : Wr1[k * 128 + (n - 128)]);
        unsigned short h = f2bf(v);
        g_B1h[n * 256 + k] = h;
        g_B1l[n * 256 + k] = f2bf(v - bf2f(h));
    }
    if (i < 128 * 128) {                               // W2 prepack
        int n = i >> 7, k = i & 127;
        float v = san((n < 64) ? Wl2[k * 64 + n] : Wr2[k * 64 + (n - 64)]);
        unsigned short h = f2bf(v);
        g_B2h[n * 128 + k] = h;
        g_B2l[n * 128 + k] = f2bf(v - bf2f(h));
    }
    if (i < (M_PAD - N_NODES) * F_H) {                 // pad_h
        g_hh[(size_t)N_NODES * F_H + i] = 0;
        g_hl[(size_t)N_NODES * F_H + i] = 0;
    }
    if (i < E) atomicAdd(&g_cnt[dst[i]], 1u);          // csr_hist
}

// ---------------- CSR build --------------------------------------------------
__global__ __launch_bounds__(256) void scanA() {
    int i = blockIdx.x * 256 + threadIdx.x;
    unsigned v = (i < N_NODES) ? g_cnt[i] : 0u;
#pragma unroll
    for (int off = 32; off > 0; off >>= 1) v += __shfl_xor(v, off, 64);
    __shared__ unsigned ws[4];
    if ((threadIdx.x & 63) == 0) ws[threadIdx.x >> 6] = v;
    __syncthreads();
    if (threadIdx.x == 0) g_part[blockIdx.x] = ws[0] + ws[1] + ws[2] + ws[3];
}
// scanC2: inline prefix-of-partials + rowstart + bcursor init + cnt self-zero
__global__ __launch_bounds__(256) void scanC2(int E) {
    __shared__ unsigned lds[256];
    __shared__ unsigned ws[4];
    int t = threadIdx.x, bid = blockIdx.x;
    unsigned pv = (t < bid) ? g_part[t] : 0u;          // bid <= 195 < 256
#pragma unroll
    for (int off = 32; off > 0; off >>= 1) pv += __shfl_xor(pv, off, 64);
    if ((t & 63) == 0) ws[t >> 6] = pv;
    int i = bid * 256 + t;
    unsigned v = (i < N_NODES) ? g_cnt[i] : 0u;
    if (i < N_NODES) g_cnt[i] = 0u;                    // self-clean for next run
    lds[t] = v;
    __syncthreads();
    unsigned base = ws[0] + ws[1] + ws[2] + ws[3];
    for (int off = 1; off < 256; off <<= 1) {
        unsigned u = (t >= off) ? lds[t - off] : 0u;
        __syncthreads();
        lds[t] += u;
        __syncthreads();
    }
    if (i < N_NODES) g_rowstart[i] = lds[t] - v + base;
    if (t == 0) g_bcursor[bid] = base;                 // bucket start cursor
    if (i == 0) g_rowstart[N_NODES] = (unsigned)E;
}

// ---------------- fused sortA + gemm1 (512 threads) --------------------------
// sortA needs scanC2; gemm1 needs only prep_hist -> co-scheduled in one kernel
// (latency-bound sort blocks overlap MFMA-heavy gemm blocks).
// gemm1 tile: 128x256 (full N in one block, 8 waves 2Mx4N, 391 blocks):
// x read AND converted exactly once (round-7 grid did both twice); B staging
// bytes unchanged vs round-7 (round-8's 64x256 doubled them -> regressed).
__global__ __launch_bounds__(512) void sortA_gemm1(const int* __restrict__ src,
                                                   const int* __restrict__ dst,
                                                   int E, int nSort,
                                                   const float* __restrict__ x) {
    __shared__ __align__(16) unsigned char s_raw[FUSED_LDS];
    int t = threadIdx.x;

    if ((int)blockIdx.x < nSort) {
        // ================= sortA body (block-local LDS counting sort) ======
        unsigned* l_cnt  = (unsigned*)s_raw;                 // NBUCK
        unsigned* l_base = l_cnt + NBUCK;                    // NBUCK
        int*      l_gadj = (int*)(l_base + NBUCK);           // NBUCK
        unsigned* sc     = (unsigned*)(l_gadj + NBUCK);      // 256
        unsigned* stageW = sc + 256;                         // CH_E words
        unsigned char* stageB = (unsigned char*)(stageW + CH_E); // CH_E bytes
        int e0 = blockIdx.x * CH_E;
        int e1 = min(e0 + CH_E, E);
        int n = e1 - e0;
        for (int i = t; i < NBUCK; i += 512) l_cnt[i] = 0u;
        __syncthreads();
        for (int e = e0 + t; e < e1; e += 512)
            atomicAdd(&l_cnt[dst[e] >> 8], 1u);
        __syncthreads();
        {   // exclusive prefix of l_cnt -> l_base (256-thread network,
            // all 512 threads execute the same __syncthreads sequence)
            unsigned v = (t < NBUCK) ? l_cnt[t] : 0u;
            if (t < 256) sc[t] = v;
            __syncthreads();
            for (int off = 1; off < 256; off <<= 1) {
                unsigned u = (t >= off && t < 256) ? sc[t - off] : 0u;
                __syncthreads();
                if (t < 256) sc[t] += u;
                __syncthreads();
            }
            if (t < NBUCK) l_base[t] = sc[t] - v;
        }
        __syncthreads();
        for (int b = t; b < NBUCK; b += 512) {   // claim global runs
            unsigned c = l_cnt[b];
            unsigned gb = c ? atomicAdd(&g_bcursor[b], c) : 0u;
            l_gadj[b] = (int)gb - (int)l_base[b];
            l_cnt[b] = l_base[b];                // becomes local cursor
        }
        __syncthreads();
        for (int e = e0 + t; e < e1; e += 512) { // scatter into LDS stage
            int d = dst[e];
            int b = d >> 8;
            unsigned p = atomicAdd(&l_cnt[b], 1u);
            stageW[p] = (unsigned)src[e] | ((unsigned)d << 16);
            stageB[p] = (unsigned char)b;
        }
        __syncthreads();
        for (int i = t; i < n; i += 512) {       // linear copy out
            int b = stageB[i];
            g_bucketed[l_gadj[b] + i] = stageW[i];
        }
        return;
    }

    // ================= gemm1 body: 128x256, 8 waves (2M x 4N) ==============
    typedef unsigned short row40[40];
    row40* As_h = (row40*)s_raw;                       // 128 rows, 10240 B
    row40* As_l = (row40*)(s_raw + 10240);
    row40* Bs_h = (row40*)(s_raw + 20480);             // 256 rows, 20480 B
    row40* Bs_l = (row40*)(s_raw + 40960);

    const int m0 = (blockIdx.x - nSort) * 128;
    const int wave = t >> 6, lane = t & 63;
    const int wm = (wave >> 2) * 64, wn = (wave & 3) * 64;
    const int lr = lane & 15, g8 = (lane >> 4) * 8;
    const int srowA = t >> 2, skA = (t & 3) * 8;   // A: 128 rows x 8 f32/thread
    const int srowB = t >> 1, skB = (t & 1) * 16;  // B: 256 rows x 16 k/thread

    f32x4 acc[4][4];
#pragma unroll
    for (int i = 0; i < 4; ++i)
#pragma unroll
        for (int j = 0; j < 4; ++j) acc[i][j] = (f32x4){0.f, 0.f, 0.f, 0.f};

    for (int kb = 0; kb < 256; kb += 32) {
        __syncthreads();
        {   // A stage: f32 -> (hi,lo) bf16 in-flight (bit-identical split)
            int grow = m0 + srowA;
            float f[8];
            if (grow < N_NODES) {
                const float4* xp = (const float4*)(x + (size_t)grow * F_IN + kb + skA);
                float4 v0 = xp[0], v1 = xp[1];
                f[0] = v0.x; f[1] = v0.y; f[2] = v0.z; f[3] = v0.w;
                f[4] = v1.x; f[5] = v1.y; f[6] = v1.z; f[7] = v1.w;
            } else {
#pragma unroll
                for (int j = 0; j < 8; ++j) f[j] = 0.f;
            }
            unsigned hw[4], lw[4];
#pragma unroll
            for (int j = 0; j < 4; ++j) {
                float a = san(f[2 * j]), b = san(f[2 * j + 1]);
                unsigned short ha = f2bf(a), hb = f2bf(b);
                unsigned short la = f2bf(a - bf2f(ha)), lb = f2bf(b - bf2f(hb));
                hw[j] = ((unsigned)hb << 16) | ha;
                lw[j] = ((unsigned)lb << 16) | la;
            }
            *(uint4*)&As_h[srowA][skA] = make_uint4(hw[0], hw[1], hw[2], hw[3]);
            *(uint4*)&As_l[srowA][skA] = make_uint4(lw[0], lw[1], lw[2], lw[3]);
        }
        {   // B stage: 16 k per thread (already split bf16)
            size_t gb = (size_t)srowB * 256 + kb + skB;
            *(uint4*)&Bs_h[srowB][skB]     = *(const uint4*)(g_B1h + gb);
            *(uint4*)&Bs_h[srowB][skB + 8] = *(const uint4*)(g_B1h + gb + 8);
            *(uint4*)&Bs_l[srowB][skB]     = *(const uint4*)(g_B1l + gb);
            *(uint4*)&Bs_l[srowB][skB + 8] = *(const uint4*)(g_B1l + gb + 8);
        }
        __syncthreads();

        bf16x8 af_h[4], af_l[4], bf_h[4], bf_l[4];
#pragma unroll
        for (int i = 0; i < 4; ++i) {
            af_h[i] = *(const bf16x8*)&As_h[wm + i * 16 + lr][g8];
            af_l[i] = *(const bf16x8*)&As_l[wm + i * 16 + lr][g8];
        }
#pragma unroll
        for (int j = 0; j < 4; ++j) {
            bf_h[j] = *(const bf16x8*)&Bs_h[wn + j * 16 + lr][g8];
            bf_l[j] = *(const bf16x8*)&Bs_l[wn + j * 16 + lr][g8];
        }
#pragma unroll
        for (int i = 0; i < 4; ++i)
#pragma unroll
            for (int j = 0; j < 4; ++j) {
                acc[i][j] = __builtin_amdgcn_mfma_f32_16x16x32_bf16(af_h[i], bf_h[j], acc[i][j], 0, 0, 0);
                acc[i][j] = __builtin_amdgcn_mfma_f32_16x16x32_bf16(af_h[i], bf_l[j], acc[i][j], 0, 0, 0);
                acc[i][j] = __builtin_amdgcn_mfma_f32_16x16x32_bf16(af_l[i], bf_h[j], acc[i][j], 0, 0, 0);
            }
    }

    const int drow = (lane >> 4) * 4;
#pragma unroll
    for (int i = 0; i < 4; ++i)
#pragma unroll
        for (int j = 0; j < 4; ++j) {
            int gn = wn + j * 16 + lr;
#pragma unroll
            for (int r = 0; r < 4; ++r) {
                int m = m0 + wm + i * 16 + drow + r;
                if (m < N_NODES) {
                    if (gn < F_H) g_xl1b[(size_t)m * F_H + gn] = f2bf(acc[i][j][r]);
                    else          g_xr1[(size_t)m * F_H + (gn - F_H)] = acc[i][j][r];
                }
            }
        }
}

__global__ __launch_bounds__(256) void sortB() {
    __shared__ unsigned l_cur[256];
    int b = blockIdx.x;
    int d0 = b * 256;
    int t = threadIdx.x;
    l_cur[t] = g_rowstart[min(d0 + t, N_NODES)];
    unsigned bstart = g_rowstart[min(d0, N_NODES)];
    unsigned bend   = g_rowstart[min(d0 + 256, N_NODES)];
    __syncthreads();
    for (unsigned i = bstart + t; i < bend; i += 256) {
        unsigned e = g_bucketed[i];
        unsigned d = e >> 16;
        unsigned pos = atomicAdd(&l_cur[d - d0], 1u);
        g_src_sorted[pos] = (int)(e & 0xFFFFu);
    }
}

// ---------------- gemm2: 128x128 tile (A read once) -------------------------
__global__ __launch_bounds__(256) void gemm2() {
    __shared__ __align__(16) unsigned short As_h[128][40];
    __shared__ __align__(16) unsigned short As_l[128][40];
    __shared__ __align__(16) unsigned short Bs_h[128][40];
    __shared__ __align__(16) unsigned short Bs_l[128][40];

    const int m0 = blockIdx.x * 128;
    const int t = threadIdx.x;
    const int wave = t >> 6, lane = t & 63;
    const int wm = (wave >> 1) * 64, wn = (wave & 1) * 64;
    const int lr = lane & 15, g8 = (lane >> 4) * 8;
    const int srow = t >> 1, shalf = (t & 1) * 16;

    f32x4 acc[4][4];
#pragma unroll
    for (int i = 0; i < 4; ++i)
#pragma unroll
        for (int j = 0; j < 4; ++j) acc[i][j] = (f32x4){0.f, 0.f, 0.f, 0.f};

    for (int kb = 0; kb < 128; kb += 32) {
        __syncthreads();
        {
            size_t ga = (size_t)(m0 + srow) * 128 + kb + shalf;
            *(uint4*)&As_h[srow][shalf]     = *(const uint4*)(g_hh + ga);
            *(uint4*)&As_h[srow][shalf + 8] = *(const uint4*)(g_hh + ga + 8);
            *(uint4*)&As_l[srow][shalf]     = *(const uint4*)(g_hl + ga);
            *(uint4*)&As_l[srow][shalf + 8] = *(const uint4*)(g_hl + ga + 8);
            size_t gb = (size_t)srow * 128 + kb + shalf;
            *(uint4*)&Bs_h[srow][shalf]     = *(const uint4*)(g_B2h + gb);
            *(uint4*)&Bs_h[srow][shalf + 8] = *(const uint4*)(g_B2h + gb + 8);
            *(uint4*)&Bs_l[srow][shalf]     = *(const uint4*)(g_B2l + gb);
            *(uint4*)&Bs_l[srow][shalf + 8] = *(const uint4*)(g_B2l + gb + 8);
        }
        __syncthreads();

        bf16x8 af_h[4], af_l[4], bf_h[4], bf_l[4];
#pragma unroll
        for (int i = 0; i < 4; ++i) {
            af_h[i] = *(const bf16x8*)&As_h[wm + i * 16 + lr][g8];
            af_l[i] = *(const bf16x8*)&As_l[wm + i * 16 + lr][g8];
        }
#pragma unroll
        for (int j = 0; j < 4; ++j) {
            bf_h[j] = *(const bf16x8*)&Bs_h[wn + j * 16 + lr][g8];
            bf_l[j] = *(const bf16x8*)&Bs_l[wn + j * 16 + lr][g8];
        }
#pragma unroll
        for (int i = 0; i < 4; ++i)
#pragma unroll
            for (int j = 0; j < 4; ++j) {
                acc[i][j] = __builtin_amdgcn_mfma_f32_16x16x32_bf16(af_h[i], bf_h[j], acc[i][j], 0, 0, 0);
                acc[i][j] = __builtin_amdgcn_mfma_f32_16x16x32_bf16(af_h[i], bf_l[j], acc[i][j], 0, 0, 0);
                acc[i][j] = __builtin_amdgcn_mfma_f32_16x16x32_bf16(af_l[i], bf_h[j], acc[i][j], 0, 0, 0);
            }
    }

    const int drow = (lane >> 4) * 4;
#pragma unroll
    for (int i = 0; i < 4; ++i)
#pragma unroll
        for (int j = 0; j < 4; ++j) {
            int gn = wn + j * 16 + lr;
#pragma unroll
            for (int r = 0; r < 4; ++r) {
                int m = m0 + wm + i * 16 + drow + r;
                if (m < N_NODES) {
                    if (gn < F_OUT) g_xl2b[(size_t)m * F_OUT + gn] = f2bf(acc[i][j][r]);
                    else            g_xr2[(size_t)m * F_OUT + (gn - F_OUT)] = acc[i][j][r];
                }
            }
        }
}

// ---------------- fused attention+aggregate, layer 1 ------------------------
// unroll-2 octet batching + barrier-free same-wave LDS handoff.
// At the L2<->L3 fabric floor (~86us, FETCH 226MB @ ~3.0 TB/s).
__global__ __launch_bounds__(256) void att_agg1(const float* __restrict__ att,
                                                const float* __restrict__ bias) {
    __shared__ float s_out[4][F_H];
    int wid = threadIdx.x >> 6, lane = threadIdx.x & 63;
    int g = lane >> 3;
    int fi = lane & 7;
    int f0 = fi * 16;

    f32x2 at2[8];
    {
        const float4* atp = (const float4*)(att + f0);
#pragma unroll
        for (int q = 0; q < 4; ++q) {
            float4 a = atp[q];
            at2[2 * q]     = (f32x2){san(a.x), san(a.y)};
            at2[2 * q + 1] = (f32x2){san(a.z), san(a.w)};
        }
    }

    for (int qd = blockIdx.x; qd < NQUAD; qd += gridDim.x) {
        int w = qd * 4 + wid;

        f32x2 xr2[8];
        {
            const float4* xrp = (const float4*)(g_xr1 + (size_t)w * F_H + f0);
#pragma unroll
            for (int q = 0; q < 4; ++q) {
                float4 v = xrp[q];
                xr2[2 * q]     = (f32x2){v.x, v.y};
                xr2[2 * q + 1] = (f32x2){v.z, v.w};
            }
        }

        int beg = (int)g_rowstart[w], end = (int)g_rowstart[w + 1];
        float m = -INFINITY, ssum = 0.f;
        f32x2 acc2[8];
#pragma unroll
        for (int q = 0; q < 8; ++q) acc2[q] = (f32x2){0.f, 0.f};

        for (int c0 = beg; c0 < end; c0 += 64) {
            int nc = min(64, end - c0);
            int mysrc = (lane < nc) ? g_src_sorted[c0 + lane] : 0;
            for (int r0 = 0; r0 < nc; r0 += 16) {
                int eA = r0 + g, eB = r0 + 8 + g;          // eB <= 63 always
                int sA = __shfl(mysrc, eA, 64);
                int sB = __shfl(mysrc, eB, 64);
                const uint4* rpA = (const uint4*)(g_xl1b + (size_t)sA * F_H + f0);
                const uint4* rpB = (const uint4*)(g_xl1b + (size_t)sB * F_H + f0);
                uint4 a0 = rpA[0], a1 = rpA[1];
                uint4 b0 = rpB[0], b1 = rpB[1];
                f32x2 rA[8];
                rA[0] = (f32x2){blo(a0.x), bhi(a0.x)};
                rA[1] = (f32x2){blo(a0.y), bhi(a0.y)};
                rA[2] = (f32x2){blo(a0.z), bhi(a0.z)};
                rA[3] = (f32x2){blo(a0.w), bhi(a0.w)};
                rA[4] = (f32x2){blo(a1.x), bhi(a1.x)};
                rA[5] = (f32x2){blo(a1.y), bhi(a1.y)};
                rA[6] = (f32x2){blo(a1.z), bhi(a1.z)};
                rA[7] = (f32x2){blo(a1.w), bhi(a1.w)};
                float dA1 = 0.f, dA2 = 0.f;
#pragma unroll
                for (int q = 0; q < 8; ++q) {
                    f32x2 z = rA[q] + xr2[q];
                    dA1 = fmaf(z.x, at2[q].x, dA1);
                    dA2 = fmaf(fabsf(z.x), at2[q].x, dA2);
                    dA1 = fmaf(z.y, at2[q].y, dA1);
                    dA2 = fmaf(fabsf(z.y), at2[q].y, dA2);
                }
                float dA = fmaf(0.6f, dA1, 0.4f * dA2);
                f32x2 rB[8];
                rB[0] = (f32x2){blo(b0.x), bhi(b0.x)};
                rB[1] = (f32x2){blo(b0.y), bhi(b0.y)};
                rB[2] = (f32x2){blo(b0.z), bhi(b0.z)};
                rB[3] = (f32x2){blo(b0.w), bhi(b0.w)};
                rB[4] = (f32x2){blo(b1.x), bhi(b1.x)};
                rB[5] = (f32x2){blo(b1.y), bhi(b1.y)};
                rB[6] = (f32x2){blo(b1.z), bhi(b1.z)};
                rB[7] = (f32x2){blo(b1.w), bhi(b1.w)};
                float dB1 = 0.f, dB2 = 0.f;
#pragma unroll
                for (int q = 0; q < 8; ++q) {
                    f32x2 z = rB[q] + xr2[q];
                    dB1 = fmaf(z.x, at2[q].x, dB1);
                    dB2 = fmaf(fabsf(z.x), at2[q].x, dB2);
                    dB1 = fmaf(z.y, at2[q].y, dB1);
                    dB2 = fmaf(fabsf(z.y), at2[q].y, dB2);
                }
                float dB = fmaf(0.6f, dB1, 0.4f * dB2);
                dA += __shfl_xor(dA, 1, 64);
                dA += __shfl_xor(dA, 2, 64);
                dA += __shfl_xor(dA, 4, 64);
                dB += __shfl_xor(dB, 1, 64);
                dB += __shfl_xor(dB, 2, 64);
                dB += __shfl_xor(dB, 4, 64);
                float eAv = (eA < nc) ? dA : -INFINITY;
                float eBv = (eB < nc) ? dB : -INFINITY;
                float M = fmaxf(eAv, eBv);
                M = fmaxf(M, __shfl_xor(M, 8, 64));
                M = fmaxf(M, __shfl_xor(M, 16, 64));
                M = fmaxf(M, __shfl_xor(M, 32, 64));
                if (M > m + 8.f) {                         // defer-max (T13)
                    float sc = __expf(m - M);              // 0 on first round
                    m = M;
                    ssum *= sc;
#pragma unroll
                    for (int q = 0; q < 8; ++q) acc2[q] *= sc;
                }
                float pA = __expf(eAv - m);                // 0 for invalid
                float pB = __expf(eBv - m);
                ssum += pA + pB;
#pragma unroll
                for (int q = 0; q < 8; ++q) {
                    acc2[q] += rA[q] * pA;
                    acc2[q] += rB[q] * pB;
                }
            }
        }
#pragma unroll
        for (int off = 8; off < 64; off <<= 1) {
            ssum += __shfl_xor(ssum, off, 64);
#pragma unroll
            for (int q = 0; q < 8; ++q) {
                acc2[q].x += __shfl_xor(acc2[q].x, off, 64);
                acc2[q].y += __shfl_xor(acc2[q].y, off, 64);
            }
        }
        float inv = 1.f / (ssum + EPS_F);
        if (g == 0) {
            float2* op = (float2*)&s_out[wid][f0];
#pragma unroll
            for (int q = 0; q < 8; ++q) {
                float2 v;
                v.x = acc2[q].x * inv; v.y = acc2[q].y * inv;
                op[q] = v;
            }
        }
        // same-wave LDS handoff: no barrier needed (per-wave DS ordering)
        int f2 = lane * 2;
        float2 o = *(float2*)&s_out[wid][f2];
        o.x = fmaxf(o.x + san(bias[f2]), 0.f);
        o.y = fmaxf(o.y + san(bias[f2 + 1]), 0.f);
        unsigned short hx = f2bf(o.x), hy = f2bf(o.y);
        unsigned short lx = f2bf(o.x - bf2f(hx)), ly = f2bf(o.y - bf2f(hy));
        size_t base = (size_t)w * F_H + f2;
        *(unsigned*)(g_hh + base) = ((unsigned)hy << 16) | hx;
        *(unsigned*)(g_hl + base) = ((unsigned)ly << 16) | lx;
    }
}

// ---------------- fused attention+aggregate, layer 2 (F=64) -----------------
__global__ __launch_bounds__(256) void att_agg2(const float* __restrict__ att,
                                                const float* __restrict__ bias,
                                                float* __restrict__ out) {
    __shared__ float s_out[4][F_OUT];
    int wid = threadIdx.x >> 6, lane = threadIdx.x & 63;
    int g = lane >> 3;
    int fi = lane & 7;
    int f0 = fi * 8;

    f32x2 at2[4];
    {
        const float4* atp = (const float4*)(att + f0);
#pragma unroll
        for (int q = 0; q < 2; ++q) {
            float4 a = atp[q];
            at2[2 * q]     = (f32x2){san(a.x), san(a.y)};
            at2[2 * q + 1] = (f32x2){san(a.z), san(a.w)};
        }
    }

    for (int qd = blockIdx.x; qd < NQUAD; qd += gridDim.x) {
        int w = qd * 4 + wid;

        f32x2 xr2[4];
        {
            const float4* xrp = (const float4*)(g_xr2 + (size_t)w * F_OUT + f0);
#pragma unroll
            for (int q = 0; q < 2; ++q) {
                float4 v = xrp[q];
                xr2[2 * q]     = (f32x2){v.x, v.y};
                xr2[2 * q + 1] = (f32x2){v.z, v.w};
            }
        }

        int beg = (int)g_rowstart[w], end = (int)g_rowstart[w + 1];
        float m = -INFINITY, ssum = 0.f;
        f32x2 acc2[4];
#pragma unroll
        for (int q = 0; q < 4; ++q) acc2[q] = (f32x2){0.f, 0.f};

        for (int c0 = beg; c0 < end; c0 += 64) {
            int nc = min(64, end - c0);
            int mysrc = (lane < nc) ? g_src_sorted[c0 + lane] : 0;
            for (int r0 = 0; r0 < nc; r0 += 16) {
                int eA = r0 + g, eB = r0 + 8 + g;
                int sA = __shfl(mysrc, eA, 64);
                int sB = __shfl(mysrc, eB, 64);
                uint4 a0 = *(const uint4*)(g_xl2b + (size_t)sA * F_OUT + f0);
                uint4 b0 = *(const uint4*)(g_xl2b + (size_t)sB * F_OUT + f0);
                f32x2 rA[4], rB[4];
                rA[0] = (f32x2){blo(a0.x), bhi(a0.x)};
                rA[1] = (f32x2){blo(a0.y), bhi(a0.y)};
                rA[2] = (f32x2){blo(a0.z), bhi(a0.z)};
                rA[3] = (f32x2){blo(a0.w), bhi(a0.w)};
                rB[0] = (f32x2){blo(b0.x), bhi(b0.x)};
                rB[1] = (f32x2){blo(b0.y), bhi(b0.y)};
                rB[2] = (f32x2){blo(b0.z), bhi(b0.z)};
                rB[3] = (f32x2){blo(b0.w), bhi(b0.w)};
                float dA1 = 0.f, dA2 = 0.f, dB1 = 0.f, dB2 = 0.f;
#pragma unroll
                for (int q = 0; q < 4; ++q) {
                    f32x2 zA = rA[q] + xr2[q];
                    dA1 = fmaf(zA.x, at2[q].x, dA1);
                    dA2 = fmaf(fabsf(zA.x), at2[q].x, dA2);
                    dA1 = fmaf(zA.y, at2[q].y, dA1);
                    dA2 = fmaf(fabsf(zA.y), at2[q].y, dA2);
                    f32x2 zB = rB[q] + xr2[q];
                    dB1 = fmaf(zB.x, at2[q].x, dB1);
                    dB2 = fmaf(fabsf(zB.x), at2[q].x, dB2);
                    dB1 = fmaf(zB.y, at2[q].y, dB1);
                    dB2 = fmaf(fabsf(zB.y), at2[q].y, dB2);
                }
                float dA = fmaf(0.6f, dA1, 0.4f * dA2);
                float dB = fmaf(0.6f, dB1, 0.4f * dB2);
                dA += __shfl_xor(dA, 1, 64);
                dA += __shfl_xor(dA, 2, 64);
                dA += __shfl_xor(dA, 4, 64);
                dB += __shfl_xor(dB, 1, 64);
                dB += __shfl_xor(dB, 2, 64);
                dB += __shfl_xor(dB, 4, 64);
                float eAv = (eA < nc) ? dA : -INFINITY;
                float eBv = (eB < nc) ? dB : -INFINITY;
                float M = fmaxf(eAv, eBv);
                M = fmaxf(M, __shfl_xor(M, 8, 64));
                M = fmaxf(M, __shfl_xor(M, 16, 64));
                M = fmaxf(M, __shfl_xor(M, 32, 64));
                if (M > m + 8.f) {                         // defer-max (T13)
                    float sc = __expf(m - M);
                    m = M;
                    ssum *= sc;
#pragma unroll
                    for (int q = 0; q < 4; ++q) acc2[q] *= sc;
                }
                float pA = __expf(eAv - m);
                float pB = __expf(eBv - m);
                ssum += pA + pB;
#pragma unroll
                for (int q = 0; q < 4; ++q) {
                    acc2[q] += rA[q] * pA;
                    acc2[q] += rB[q] * pB;
                }
            }
        }
#pragma unroll
        for (int off = 8; off < 64; off <<= 1) {
            ssum += __shfl_xor(ssum, off, 64);
#pragma unroll
            for (int q = 0; q < 4; ++q) {
                acc2[q].x += __shfl_xor(acc2[q].x, off, 64);
                acc2[q].y += __shfl_xor(acc2[q].y, off, 64);
            }
        }
        float inv = 1.f / (ssum + EPS_F);
        if (g == 0) {
            float2* op = (float2*)&s_out[wid][f0];
#pragma unroll
            for (int q = 0; q < 2; ++q) {
                float2 v0, v1;
                v0.x = acc2[2 * q].x * inv;     v0.y = acc2[2 * q].y * inv;
                v1.x = acc2[2 * q + 1].x * inv; v1.y = acc2[2 * q + 1].y * inv;
                op[2 * q] = v0;
                op[2 * q + 1] = v1;
            }
        }
        // same-wave LDS handoff: no barrier needed
        out[(size_t)w * F_OUT + lane] = s_out[wid][lane] + san(bias[lane]);
    }
}

// ---------------- launch ------------------------------------------------------
extern "C" void kernel_launch(void* const* d_in, const int* in_sizes, int n_in,
                              void* d_out, int out_size, void* d_ws, size_t ws_size,
                              hipStream_t stream) {
    const float* x    = (const float*)d_in[0];
    const int*   ei   = (const int*)d_in[1];
    const float* Wl1  = (const float*)d_in[2];
    const float* Wr1  = (const float*)d_in[3];
    const float* att1 = (const float*)d_in[4];
    const float* b1   = (const float*)d_in[5];
    const float* Wl2  = (const float*)d_in[6];
    const float* Wr2  = (const float*)d_in[7];
    const float* att2 = (const float*)d_in[8];
    const float* b2   = (const float*)d_in[9];

    int E = in_sizes[1] / 2;
    const int* src = ei;
    const int* dst = ei + E;

    int gE = (E + 255) / 256;
    int gSA = (E + CH_E - 1) / CH_E;

    prep_hist<<<gE, 256, 0, stream>>>(dst, E, Wl1, Wr1, Wl2, Wr2);
    scanA<<<NPART, 256, 0, stream>>>();
    scanC2<<<NPART, 256, 0, stream>>>(E);
    sortA_gemm1<<<gSA + MT, 512, 0, stream>>>(src, dst, E, gSA, x);
    sortB<<<NBUCK, 256, 0, stream>>>();

    // ---- layer 1 ----
    att_agg1<<<ATT_GRID, 256, 0, stream>>>(att1, b1);

    // ---- layer 2 ----
    gemm2<<<MT, 256, 0, stream>>>();
    att_agg2<<<ATT_GRID, 256, 0, stream>>>(att2, b2, (float*)d_out);
}

// Round 11
// 399.320 us; speedup vs baseline: 1.0045x; 1.0045x over previous
//
#include <hip/hip_runtime.h>

#define N_NODES 50000
#define M_PAD 50048            // 391 * 128
#define MT 391
#define GEMM1_BLOCKS 782       // (2 N-blocks) x (391 M-blocks), N fastest
#define F_IN 256
#define F_H 128
#define F_OUT 64
#define E_MAX 1600000
#define NEG_SLOPE 0.2f
#define EPS_F 1e-16f
#define NPART 196              // ceil(50000/256)
#define NBUCK 196              // coarse buckets: dst >> 8
#define CH_E 4096              // edges per sortA block -> 391 blocks
#define NQUAD 12500            // N_NODES / 4
#define ATT_GRID 2048          // persistent blocks
#define FUSED_LDS 40960        // max(gemm1 40KB, sortA ~24KB)

typedef __bf16 bf16x8 __attribute__((ext_vector_type(8)));
typedef float f32x4 __attribute__((ext_vector_type(4)));
typedef float f32x2 __attribute__((ext_vector_type(2)));

// ---------------- device-global scratch ------------------------------------
__device__ unsigned short g_B1h[256 * 256];
__device__ unsigned short g_B1l[256 * 256];
__device__ unsigned short g_B2h[128 * 128];
__device__ unsigned short g_B2l[128 * 128];
__device__ unsigned short g_hh[(size_t)M_PAD * F_H];
__device__ unsigned short g_hl[(size_t)M_PAD * F_H];
// gather tables: xl in bf16 (halves gather bytes), xr in f32 (read once/dst)
__device__ unsigned short g_xl1b[(size_t)N_NODES * F_H];
__device__ float g_xr1[(size_t)N_NODES * F_H];
__device__ unsigned short g_xl2b[(size_t)N_NODES * F_OUT];
__device__ float g_xr2[(size_t)N_NODES * F_OUT];
// CSR by dst
__device__ unsigned g_cnt[N_NODES];        // zero at load; self-zeroed by scanC2
__device__ unsigned g_part[NPART];
__device__ unsigned g_rowstart[N_NODES + 1];
__device__ unsigned g_bcursor[NBUCK];
__device__ unsigned g_bucketed[E_MAX];     // packed src | dst<<16
__device__ int g_src_sorted[E_MAX];

// ---------------- helpers ---------------------------------------------------
__device__ inline float san(float v) { return fminf(fmaxf(v, -64.f), 64.f); }
__device__ inline unsigned short f2bf(float f) {        // RNE f32->bf16
    unsigned u = __float_as_uint(f);
    return (unsigned short)((u + 0x7fffu + ((u >> 16) & 1u)) >> 16);
}
__device__ inline float bf2f(unsigned short h) {
    return __uint_as_float(((unsigned)h) << 16);
}
__device__ inline float blo(unsigned w) { return __uint_as_float(w << 16); }
__device__ inline float bhi(unsigned w) { return __uint_as_float(w & 0xffff0000u); }

// ---------------- fused prep: weight prepack + pad_h + csr_hist -------------
__global__ __launch_bounds__(256) void prep_hist(const int* __restrict__ dst, int E,
                                                 const float* __restrict__ Wl1,
                                                 const float* __restrict__ Wr1,
                                                 const float* __restrict__ Wl2,
                                                 const float* __restrict__ Wr2) {
    int i = blockIdx.x * 256 + threadIdx.x;
    if (i < 256 * 256) {                               // W1 prepack
        int n = i >> 8, k = i & 255;
        float v = san((n < 128) ? Wl1[k * 128 + n] : Wr1[k * 128 + (n - 128)]);
        unsigned short h = f2bf(v);
        g_B1h[n * 256 + k] = h;
        g_B1l[n * 256 + k] = f2bf(v - bf2f(h));
    }
    if (i < 128 * 128) {                               // W2 prepack
        int n = i >> 7, k = i & 127;
        float v = san((n < 64) ? Wl2[k * 64 + n] : Wr2[k * 64 + (n - 64)]);
        unsigned short h = f2bf(v);
        g_B2h[n * 128 + k] = h;
        g_B2l[n * 128 + k] = f2bf(v - bf2f(h));
    }
    if (i < (M_PAD - N_NODES) * F_H) {                 // pad_h
        g_hh[(size_t)N_NODES * F_H + i] = 0;
        g_hl[(size_t)N_NODES * F_H + i] = 0;
    }
    if (i < E) atomicAdd(&g_cnt[dst[i]], 1u);          // csr_hist
}

// ---------------- CSR build --------------------------------------------------
__global__ __launch_bounds__(256) void scanA() {
    int i = blockIdx.x * 256 + threadIdx.x;
    unsigned v = (i < N_NODES) ? g_cnt[i] : 0u;
#pragma unroll
    for (int off = 32; off > 0; off >>= 1) v += __shfl_xor(v, off, 64);
    __shared__ unsigned ws[4];
    if ((threadIdx.x & 63) == 0) ws[threadIdx.x >> 6] = v;
    __syncthreads();
    if (threadIdx.x == 0) g_part[blockIdx.x] = ws[0] + ws[1] + ws[2] + ws[3];
}
// scanC2: inline prefix-of-partials + rowstart + bcursor init + cnt self-zero
__global__ __launch_bounds__(256) void scanC2(int E) {
    __shared__ unsigned lds[256];
    __shared__ unsigned ws[4];
    int t = threadIdx.x, bid = blockIdx.x;
    unsigned pv = (t < bid) ? g_part[t] : 0u;          // bid <= 195 < 256
#pragma unroll
    for (int off = 32; off > 0; off >>= 1) pv += __shfl_xor(pv, off, 64);
    if ((t & 63) == 0) ws[t >> 6] = pv;
    int i = bid * 256 + t;
    unsigned v = (i < N_NODES) ? g_cnt[i] : 0u;
    if (i < N_NODES) g_cnt[i] = 0u;                    // self-clean for next run
    lds[t] = v;
    __syncthreads();
    unsigned base = ws[0] + ws[1] + ws[2] + ws[3];
    for (int off = 1; off < 256; off <<= 1) {
        unsigned u = (t >= off) ? lds[t - off] : 0u;
        __syncthreads();
        lds[t] += u;
        __syncthreads();
    }
    if (i < N_NODES) g_rowstart[i] = lds[t] - v + base;
    if (t == 0) g_bcursor[bid] = base;                 // bucket start cursor
    if (i == 0) g_rowstart[N_NODES] = (unsigned)E;
}

// ---------------- fused sortA + gemm1 (round-9 best config) ------------------
// sortA needs scanC2; gemm1 needs only prep_hist -> co-scheduled in one kernel
// (latency-bound sort blocks overlap MFMA-heavy gemm blocks).
// gemm1: 128x128 tile, (2 N) x (391 M), N fastest. Rounds 8+10 showed tile
// reshapes (64x256, 128x256) are neutral-to-worse: k-loop is staging-slot
// bound, so this minimal-staging shape stays.
__global__ __launch_bounds__(256) void sortA_gemm1(const int* __restrict__ src,
                                                   const int* __restrict__ dst,
                                                   int E, int nSort,
                                                   const float* __restrict__ x) {
    __shared__ __align__(16) unsigned char s_raw[FUSED_LDS];
    int t = threadIdx.x;

    if ((int)blockIdx.x < nSort) {
        // ================= sortA body (block-local LDS counting sort) ======
        unsigned* l_cnt  = (unsigned*)s_raw;                 // NBUCK
        unsigned* l_base = l_cnt + NBUCK;                    // NBUCK
        int*      l_gadj = (int*)(l_base + NBUCK);           // NBUCK
        unsigned* sc     = (unsigned*)(l_gadj + NBUCK);      // 256
        unsigned* stageW = sc + 256;                         // CH_E words
        unsigned char* stageB = (unsigned char*)(stageW + CH_E); // CH_E bytes
        int e0 = blockIdx.x * CH_E;
        int e1 = min(e0 + CH_E, E);
        int n = e1 - e0;
        for (int i = t; i < NBUCK; i += 256) l_cnt[i] = 0u;
        __syncthreads();
        for (int e = e0 + t; e < e1; e += 256)
            atomicAdd(&l_cnt[dst[e] >> 8], 1u);
        __syncthreads();
        {   // exclusive prefix of l_cnt -> l_base
            unsigned v = (t < NBUCK) ? l_cnt[t] : 0u;
            sc[t] = v;
            __syncthreads();
            for (int off = 1; off < 256; off <<= 1) {
                unsigned u = (t >= off) ? sc[t - off] : 0u;
                __syncthreads();
                sc[t] += u;
                __syncthreads();
            }
            if (t < NBUCK) l_base[t] = sc[t] - v;
        }
        __syncthreads();
        for (int b = t; b < NBUCK; b += 256) {   // claim global runs
            unsigned c = l_cnt[b];
            unsigned gb = c ? atomicAdd(&g_bcursor[b], c) : 0u;
            l_gadj[b] = (int)gb - (int)l_base[b];
            l_cnt[b] = l_base[b];                // becomes local cursor
        }
        __syncthreads();
        for (int e = e0 + t; e < e1; e += 256) { // scatter into LDS stage
            int d = dst[e];
            int b = d >> 8;
            unsigned p = atomicAdd(&l_cnt[b], 1u);
            stageW[p] = (unsigned)src[e] | ((unsigned)d << 16);
            stageB[p] = (unsigned char)b;
        }
        __syncthreads();
        for (int i = t; i < n; i += 256) {       // linear copy out
            int b = stageB[i];
            g_bucketed[l_gadj[b] + i] = stageW[i];
        }
        return;
    }

    // ================= gemm1 body (128x128, N fastest) =====================
    typedef unsigned short row40[40];
    row40* As_h = (row40*)s_raw;                       // 128 rows
    row40* As_l = (row40*)(s_raw + 10240);
    row40* Bs_h = (row40*)(s_raw + 20480);
    row40* Bs_l = (row40*)(s_raw + 30720);

    int bx = blockIdx.x - nSort;              // 0..781
    const int n0 = (bx & 1) * 128;            // N fastest (A-tile L2 sharing)
    const int m0 = (bx >> 1) * 128;
    const int wave = t >> 6, lane = t & 63;
    const int wm = (wave >> 1) * 64, wn = (wave & 1) * 64;
    const int lr = lane & 15, g8 = (lane >> 4) * 8;
    const int srow = t >> 1, shalf = (t & 1) * 16;

    f32x4 acc[4][4];
#pragma unroll
    for (int i = 0; i < 4; ++i)
#pragma unroll
        for (int j = 0; j < 4; ++j) acc[i][j] = (f32x4){0.f, 0.f, 0.f, 0.f};

    for (int kb = 0; kb < 256; kb += 32) {
        __syncthreads();
        {   // A stage: f32 -> (hi,lo) bf16 in-flight (bit-identical split)
            int grow = m0 + srow;
            float f[16];
            if (grow < N_NODES) {
                const float4* xp = (const float4*)(x + (size_t)grow * F_IN + kb + shalf);
                float4 v0 = xp[0], v1 = xp[1], v2 = xp[2], v3 = xp[3];
                f[0] = v0.x;  f[1] = v0.y;  f[2] = v0.z;  f[3] = v0.w;
                f[4] = v1.x;  f[5] = v1.y;  f[6] = v1.z;  f[7] = v1.w;
                f[8] = v2.x;  f[9] = v2.y;  f[10] = v2.z; f[11] = v2.w;
                f[12] = v3.x; f[13] = v3.y; f[14] = v3.z; f[15] = v3.w;
            } else {
#pragma unroll
                for (int j = 0; j < 16; ++j) f[j] = 0.f;
            }
            unsigned hw[8], lw[8];
#pragma unroll
            for (int j = 0; j < 8; ++j) {
                float a = san(f[2 * j]), b = san(f[2 * j + 1]);
                unsigned short ha = f2bf(a), hb = f2bf(b);
                unsigned short la = f2bf(a - bf2f(ha)), lb = f2bf(b - bf2f(hb));
                hw[j] = ((unsigned)hb << 16) | ha;
                lw[j] = ((unsigned)lb << 16) | la;
            }
            *(uint4*)&As_h[srow][shalf]     = make_uint4(hw[0], hw[1], hw[2], hw[3]);
            *(uint4*)&As_h[srow][shalf + 8] = make_uint4(hw[4], hw[5], hw[6], hw[7]);
            *(uint4*)&As_l[srow][shalf]     = make_uint4(lw[0], lw[1], lw[2], lw[3]);
            *(uint4*)&As_l[srow][shalf + 8] = make_uint4(lw[4], lw[5], lw[6], lw[7]);
        }
        {
            size_t gb = (size_t)(n0 + srow) * 256 + kb + shalf;
            *(uint4*)&Bs_h[srow][shalf]     = *(const uint4*)(g_B1h + gb);
            *(uint4*)&Bs_h[srow][shalf + 8] = *(const uint4*)(g_B1h + gb + 8);
            *(uint4*)&Bs_l[srow][shalf]     = *(const uint4*)(g_B1l + gb);
            *(uint4*)&Bs_l[srow][shalf + 8] = *(const uint4*)(g_B1l + gb + 8);
        }
        __syncthreads();

        bf16x8 af_h[4], af_l[4], bf_h[4], bf_l[4];
#pragma unroll
        for (int i = 0; i < 4; ++i) {
            af_h[i] = *(const bf16x8*)&As_h[wm + i * 16 + lr][g8];
            af_l[i] = *(const bf16x8*)&As_l[wm + i * 16 + lr][g8];
        }
#pragma unroll
        for (int j = 0; j < 4; ++j) {
            bf_h[j] = *(const bf16x8*)&Bs_h[wn + j * 16 + lr][g8];
            bf_l[j] = *(const bf16x8*)&Bs_l[wn + j * 16 + lr][g8];
        }
#pragma unroll
        for (int i = 0; i < 4; ++i)
#pragma unroll
            for (int j = 0; j < 4; ++j) {
                acc[i][j] = __builtin_amdgcn_mfma_f32_16x16x32_bf16(af_h[i], bf_h[j], acc[i][j], 0, 0, 0);
                acc[i][j] = __builtin_amdgcn_mfma_f32_16x16x32_bf16(af_h[i], bf_l[j], acc[i][j], 0, 0, 0);
                acc[i][j] = __builtin_amdgcn_mfma_f32_16x16x32_bf16(af_l[i], bf_h[j], acc[i][j], 0, 0, 0);
            }
    }

    const int drow = (lane >> 4) * 4;
#pragma unroll
    for (int i = 0; i < 4; ++i)
#pragma unroll
        for (int j = 0; j < 4; ++j) {
            int gn = n0 + wn + j * 16 + lr;
#pragma unroll
            for (int r = 0; r < 4; ++r) {
                int m = m0 + wm + i * 16 + drow + r;
                if (m < N_NODES) {
                    if (gn < F_H) g_xl1b[(size_t)m * F_H + gn] = f2bf(acc[i][j][r]);
                    else          g_xr1[(size_t)m * F_H + (gn - F_H)] = acc[i][j][r];
                }
            }
        }
}

__global__ __launch_bounds__(256) void sortB() {
    __shared__ unsigned l_cur[256];
    int b = blockIdx.x;
    int d0 = b * 256;
    int t = threadIdx.x;
    l_cur[t] = g_rowstart[min(d0 + t, N_NODES)];
    unsigned bstart = g_rowstart[min(d0, N_NODES)];
    unsigned bend   = g_rowstart[min(d0 + 256, N_NODES)];
    __syncthreads();
    for (unsigned i = bstart + t; i < bend; i += 256) {
        unsigned e = g_bucketed[i];
        unsigned d = e >> 16;
        unsigned pos = atomicAdd(&l_cur[d - d0], 1u);
        g_src_sorted[pos] = (int)(e & 0xFFFFu);
    }
}

// ---------------- gemm2: 128x128 tile (A read once) -------------------------
__global__ __launch_bounds__(256) void gemm2() {
    __shared__ __align__(16) unsigned short As_h[128][40];
    __shared__ __align__(16) unsigned short As_l[128][40];
    __shared__ __align__(16) unsigned short Bs_h[128][40];
    __shared__ __align__(16) unsigned short Bs_l[128][40];

    const int m0 = blockIdx.x * 128;
    const int t = threadIdx.x;
    const int wave = t >> 6, lane = t & 63;
    const int wm = (wave >> 1) * 64, wn = (wave & 1) * 64;
    const int lr = lane & 15, g8 = (lane >> 4) * 8;
    const int srow = t >> 1, shalf = (t & 1) * 16;

    f32x4 acc[4][4];
#pragma unroll
    for (int i = 0; i < 4; ++i)
#pragma unroll
        for (int j = 0; j < 4; ++j) acc[i][j] = (f32x4){0.f, 0.f, 0.f, 0.f};

    for (int kb = 0; kb < 128; kb += 32) {
        __syncthreads();
        {
            size_t ga = (size_t)(m0 + srow) * 128 + kb + shalf;
            *(uint4*)&As_h[srow][shalf]     = *(const uint4*)(g_hh + ga);
            *(uint4*)&As_h[srow][shalf + 8] = *(const uint4*)(g_hh + ga + 8);
            *(uint4*)&As_l[srow][shalf]     = *(const uint4*)(g_hl + ga);
            *(uint4*)&As_l[srow][shalf + 8] = *(const uint4*)(g_hl + ga + 8);
            size_t gb = (size_t)srow * 128 + kb + shalf;
            *(uint4*)&Bs_h[srow][shalf]     = *(const uint4*)(g_B2h + gb);
            *(uint4*)&Bs_h[srow][shalf + 8] = *(const uint4*)(g_B2h + gb + 8);
            *(uint4*)&Bs_l[srow][shalf]     = *(const uint4*)(g_B2l + gb);
            *(uint4*)&Bs_l[srow][shalf + 8] = *(const uint4*)(g_B2l + gb + 8);
        }
        __syncthreads();

        bf16x8 af_h[4], af_l[4], bf_h[4], bf_l[4];
#pragma unroll
        for (int i = 0; i < 4; ++i) {
            af_h[i] = *(const bf16x8*)&As_h[wm + i * 16 + lr][g8];
            af_l[i] = *(const bf16x8*)&As_l[wm + i * 16 + lr][g8];
        }
#pragma unroll
        for (int j = 0; j < 4; ++j) {
            bf_h[j] = *(const bf16x8*)&Bs_h[wn + j * 16 + lr][g8];
            bf_l[j] = *(const bf16x8*)&Bs_l[wn + j * 16 + lr][g8];
        }
#pragma unroll
        for (int i = 0; i < 4; ++i)
#pragma unroll
            for (int j = 0; j < 4; ++j) {
                acc[i][j] = __builtin_amdgcn_mfma_f32_16x16x32_bf16(af_h[i], bf_h[j], acc[i][j], 0, 0, 0);
                acc[i][j] = __builtin_amdgcn_mfma_f32_16x16x32_bf16(af_h[i], bf_l[j], acc[i][j], 0, 0, 0);
                acc[i][j] = __builtin_amdgcn_mfma_f32_16x16x32_bf16(af_l[i], bf_h[j], acc[i][j], 0, 0, 0);
            }
    }

    const int drow = (lane >> 4) * 4;
#pragma unroll
    for (int i = 0; i < 4; ++i)
#pragma unroll
        for (int j = 0; j < 4; ++j) {
            int gn = wn + j * 16 + lr;
#pragma unroll
            for (int r = 0; r < 4; ++r) {
                int m = m0 + wm + i * 16 + drow + r;
                if (m < N_NODES) {
                    if (gn < F_OUT) g_xl2b[(size_t)m * F_OUT + gn] = f2bf(acc[i][j][r]);
                    else            g_xr2[(size_t)m * F_OUT + (gn - F_OUT)] = acc[i][j][r];
                }
            }
        }
}

// ---------------- fused attention+aggregate, layer 1 ------------------------
// unroll-2 octet batching + barrier-free same-wave LDS handoff.
// At the L2<->L3 fabric floor (~86us, FETCH 226MB @ ~3.0 TB/s).
__global__ __launch_bounds__(256) void att_agg1(const float* __restrict__ att,
                                                const float* __restrict__ bias) {
    __shared__ float s_out[4][F_H];
    int wid = threadIdx.x >> 6, lane = threadIdx.x & 63;
    int g = lane >> 3;
    int fi = lane & 7;
    int f0 = fi * 16;

    f32x2 at2[8];
    {
        const float4* atp = (const float4*)(att + f0);
#pragma unroll
        for (int q = 0; q < 4; ++q) {
            float4 a = atp[q];
            at2[2 * q]     = (f32x2){san(a.x), san(a.y)};
            at2[2 * q + 1] = (f32x2){san(a.z), san(a.w)};
        }
    }

    for (int qd = blockIdx.x; qd < NQUAD; qd += gridDim.x) {
        int w = qd * 4 + wid;

        f32x2 xr2[8];
        {
            const float4* xrp = (const float4*)(g_xr1 + (size_t)w * F_H + f0);
#pragma unroll
            for (int q = 0; q < 4; ++q) {
                float4 v = xrp[q];
                xr2[2 * q]     = (f32x2){v.x, v.y};
                xr2[2 * q + 1] = (f32x2){v.z, v.w};
            }
        }

        int beg = (int)g_rowstart[w], end = (int)g_rowstart[w + 1];
        float m = -INFINITY, ssum = 0.f;
        f32x2 acc2[8];
#pragma unroll
        for (int q = 0; q < 8; ++q) acc2[q] = (f32x2){0.f, 0.f};

        for (int c0 = beg; c0 < end; c0 += 64) {
            int nc = min(64, end - c0);
            int mysrc = (lane < nc) ? g_src_sorted[c0 + lane] : 0;
            for (int r0 = 0; r0 < nc; r0 += 16) {
                int eA = r0 + g, eB = r0 + 8 + g;          // eB <= 63 always
                int sA = __shfl(mysrc, eA, 64);
                int sB = __shfl(mysrc, eB, 64);
                const uint4* rpA = (const uint4*)(g_xl1b + (size_t)sA * F_H + f0);
                const uint4* rpB = (const uint4*)(g_xl1b + (size_t)sB * F_H + f0);
                uint4 a0 = rpA[0], a1 = rpA[1];
                uint4 b0 = rpB[0], b1 = rpB[1];
                f32x2 rA[8];
                rA[0] = (f32x2){blo(a0.x), bhi(a0.x)};
                rA[1] = (f32x2){blo(a0.y), bhi(a0.y)};
                rA[2] = (f32x2){blo(a0.z), bhi(a0.z)};
                rA[3] = (f32x2){blo(a0.w), bhi(a0.w)};
                rA[4] = (f32x2){blo(a1.x), bhi(a1.x)};
                rA[5] = (f32x2){blo(a1.y), bhi(a1.y)};
                rA[6] = (f32x2){blo(a1.z), bhi(a1.z)};
                rA[7] = (f32x2){blo(a1.w), bhi(a1.w)};
                float dA1 = 0.f, dA2 = 0.f;
#pragma unroll
                for (int q = 0; q < 8; ++q) {
                    f32x2 z = rA[q] + xr2[q];
                    dA1 = fmaf(z.x, at2[q].x, dA1);
                    dA2 = fmaf(fabsf(z.x), at2[q].x, dA2);
                    dA1 = fmaf(z.y, at2[q].y, dA1);
                    dA2 = fmaf(fabsf(z.y), at2[q].y, dA2);
                }
                float dA = fmaf(0.6f, dA1, 0.4f * dA2);
                f32x2 rB[8];
                rB[0] = (f32x2){blo(b0.x), bhi(b0.x)};
                rB[1] = (f32x2){blo(b0.y), bhi(b0.y)};
                rB[2] = (f32x2){blo(b0.z), bhi(b0.z)};
                rB[3] = (f32x2){blo(b0.w), bhi(b0.w)};
                rB[4] = (f32x2){blo(b1.x), bhi(b1.x)};
                rB[5] = (f32x2){blo(b1.y), bhi(b1.y)};
                rB[6] = (f32x2){blo(b1.z), bhi(b1.z)};
                rB[7] = (f32x2){blo(b1.w), bhi(b1.w)};
                float dB1 = 0.f, dB2 = 0.f;
#pragma unroll
                for (int q = 0; q < 8; ++q) {
                    f32x2 z = rB[q] + xr2[q];
                    dB1 = fmaf(z.x, at2[q].x, dB1);
                    dB2 = fmaf(fabsf(z.x), at2[q].x, dB2);
                    dB1 = fmaf(z.y, at2[q].y, dB1);
                    dB2 = fmaf(fabsf(z.y), at2[q].y, dB2);
                }
                float dB = fmaf(0.6f, dB1, 0.4f * dB2);
                dA += __shfl_xor(dA, 1, 64);
                dA += __shfl_xor(dA, 2, 64);
                dA += __shfl_xor(dA, 4, 64);
                dB += __shfl_xor(dB, 1, 64);
                dB += __shfl_xor(dB, 2, 64);
                dB += __shfl_xor(dB, 4, 64);
                float eAv = (eA < nc) ? dA : -INFINITY;
                float eBv = (eB < nc) ? dB : -INFINITY;
                float M = fmaxf(eAv, eBv);
                M = fmaxf(M, __shfl_xor(M, 8, 64));
                M = fmaxf(M, __shfl_xor(M, 16, 64));
                M = fmaxf(M, __shfl_xor(M, 32, 64));
                if (M > m + 8.f) {                         // defer-max (T13)
                    float sc = __expf(m - M);              // 0 on first round
                    m = M;
                    ssum *= sc;
#pragma unroll
                    for (int q = 0; q < 8; ++q) acc2[q] *= sc;
                }
                float pA = __expf(eAv - m);                // 0 for invalid
                float pB = __expf(eBv - m);
                ssum += pA + pB;
#pragma unroll
                for (int q = 0; q < 8; ++q) {
                    acc2[q] += rA[q] * pA;
                    acc2[q] += rB[q] * pB;
                }
            }
        }
#pragma unroll
        for (int off = 8; off < 64; off <<= 1) {
            ssum += __shfl_xor(ssum, off, 64);
#pragma unroll
            for (int q = 0; q < 8; ++q) {
                acc2[q].x += __shfl_xor(acc2[q].x, off, 64);
                acc2[q].y += __shfl_xor(acc2[q].y, off, 64);
            }
        }
        float inv = 1.f / (ssum + EPS_F);
        if (g == 0) {
            float2* op = (float2*)&s_out[wid][f0];
#pragma unroll
            for (int q = 0; q < 8; ++q) {
                float2 v;
                v.x = acc2[q].x * inv; v.y = acc2[q].y * inv;
                op[q] = v;
            }
        }
        // same-wave LDS handoff: no barrier needed (per-wave DS ordering)
        int f2 = lane * 2;
        float2 o = *(float2*)&s_out[wid][f2];
        o.x = fmaxf(o.x + san(bias[f2]), 0.f);
        o.y = fmaxf(o.y + san(bias[f2 + 1]), 0.f);
        unsigned short hx = f2bf(o.x), hy = f2bf(o.y);
        unsigned short lx = f2bf(o.x - bf2f(hx)), ly = f2bf(o.y - bf2f(hy));
        size_t base = (size_t)w * F_H + f2;
        *(unsigned*)(g_hh + base) = ((unsigned)hy << 16) | hx;
        *(unsigned*)(g_hl + base) = ((unsigned)ly << 16) | lx;
    }
}

// ---------------- fused attention+aggregate, layer 2 (F=64) -----------------
// unroll-4 (8 loads in flight): att2 has the same trip count as att1 but half
// the per-iteration compute and bytes -> more latency-quantized, and the
// VGPR cost of 4-deep is half. Round-5 A/B evidence: att2 unroll-4 ~ -10us.
__global__ __launch_bounds__(256) void att_agg2(const float* __restrict__ att,
                                                const float* __restrict__ bias,
                                                float* __restrict__ out) {
    __shared__ float s_out[4][F_OUT];
    int wid = threadIdx.x >> 6, lane = threadIdx.x & 63;
    int g = lane >> 3;
    int fi = lane & 7;
    int f0 = fi * 8;

    f32x2 at2[4];
    {
        const float4* atp = (const float4*)(att + f0);
#pragma unroll
        for (int q = 0; q < 2; ++q) {
            float4 a = atp[q];
            at2[2 * q]     = (f32x2){san(a.x), san(a.y)};
            at2[2 * q + 1] = (f32x2){san(a.z), san(a.w)};
        }
    }

    for (int qd = blockIdx.x; qd < NQUAD; qd += gridDim.x) {
        int w = qd * 4 + wid;

        f32x2 xr2[4];
        {
            const float4* xrp = (const float4*)(g_xr2 + (size_t)w * F_OUT + f0);
#pragma unroll
            for (int q = 0; q < 2; ++q) {
                float4 v = xrp[q];
                xr2[2 * q]     = (f32x2){v.x, v.y};
                xr2[2 * q + 1] = (f32x2){v.z, v.w};
            }
        }

        int beg = (int)g_rowstart[w], end = (int)g_rowstart[w + 1];
        float m = -INFINITY, ssum = 0.f;
        f32x2 acc2[4];
#pragma unroll
        for (int q = 0; q < 4; ++q) acc2[q] = (f32x2){0.f, 0.f};

        for (int c0 = beg; c0 < end; c0 += 64) {
            int nc = min(64, end - c0);
            int mysrc = (lane < nc) ? g_src_sorted[c0 + lane] : 0;
            for (int r0 = 0; r0 < nc; r0 += 32) {
                int eA = r0 + g, eB = r0 + 8 + g;
                int eC = r0 + 16 + g, eD = r0 + 24 + g;    // always < 64
                int sA = __shfl(mysrc, eA, 64);
                int sB = __shfl(mysrc, eB, 64);
                int sC = __shfl(mysrc, eC, 64);
                int sD = __shfl(mysrc, eD, 64);
                uint4 qa0 = *(const uint4*)(g_xl2b + (size_t)sA * F_OUT + f0);
                uint4 qb0 = *(const uint4*)(g_xl2b + (size_t)sB * F_OUT + f0);
                uint4 qc0 = *(const uint4*)(g_xl2b + (size_t)sC * F_OUT + f0);
                uint4 qd0 = *(const uint4*)(g_xl2b + (size_t)sD * F_OUT + f0);
                f32x2 rA[4], rB[4], rC[4], rD[4];
                rA[0] = (f32x2){blo(qa0.x), bhi(qa0.x)};
                rA[1] = (f32x2){blo(qa0.y), bhi(qa0.y)};
                rA[2] = (f32x2){blo(qa0.z), bhi(qa0.z)};
                rA[3] = (f32x2){blo(qa0.w), bhi(qa0.w)};
                rB[0] = (f32x2){blo(qb0.x), bhi(qb0.x)};
                rB[1] = (f32x2){blo(qb0.y), bhi(qb0.y)};
                rB[2] = (f32x2){blo(qb0.z), bhi(qb0.z)};
                rB[3] = (f32x2){blo(qb0.w), bhi(qb0.w)};
                rC[0] = (f32x2){blo(qc0.x), bhi(qc0.x)};
                rC[1] = (f32x2){blo(qc0.y), bhi(qc0.y)};
                rC[2] = (f32x2){blo(qc0.z), bhi(qc0.z)};
                rC[3] = (f32x2){blo(qc0.w), bhi(qc0.w)};
                rD[0] = (f32x2){blo(qd0.x), bhi(qd0.x)};
                rD[1] = (f32x2){blo(qd0.y), bhi(qd0.y)};
                rD[2] = (f32x2){blo(qd0.z), bhi(qd0.z)};
                rD[3] = (f32x2){blo(qd0.w), bhi(qd0.w)};
                float dA1 = 0.f, dA2 = 0.f, dB1 = 0.f, dB2 = 0.f;
                float dC1 = 0.f, dC2 = 0.f, dD1 = 0.f, dD2 = 0.f;
#pragma unroll
                for (int q = 0; q < 4; ++q) {
                    f32x2 zA = rA[q] + xr2[q];
                    dA1 = fmaf(zA.x, at2[q].x, dA1);
                    dA2 = fmaf(fabsf(zA.x), at2[q].x, dA2);
                    dA1 = fmaf(zA.y, at2[q].y, dA1);
                    dA2 = fmaf(fabsf(zA.y), at2[q].y, dA2);
                    f32x2 zB = rB[q] + xr2[q];
                    dB1 = fmaf(zB.x, at2[q].x, dB1);
                    dB2 = fmaf(fabsf(zB.x), at2[q].x, dB2);
                    dB1 = fmaf(zB.y, at2[q].y, dB1);
                    dB2 = fmaf(fabsf(zB.y), at2[q].y, dB2);
                    f32x2 zC = rC[q] + xr2[q];
                    dC1 = fmaf(zC.x, at2[q].x, dC1);
                    dC2 = fmaf(fabsf(zC.x), at2[q].x, dC2);
                    dC1 = fmaf(zC.y, at2[q].y, dC1);
                    dC2 = fmaf(fabsf(zC.y), at2[q].y, dC2);
                    f32x2 zD = rD[q] + xr2[q];
                    dD1 = fmaf(zD.x, at2[q].x, dD1);
                    dD2 = fmaf(fabsf(zD.x), at2[q].x, dD2);
                    dD1 = fmaf(zD.y, at2[q].y, dD1);
                    dD2 = fmaf(fabsf(zD.y), at2[q].y, dD2);
                }
                float dA = fmaf(0.6f, dA1, 0.4f * dA2);
                float dB = fmaf(0.6f, dB1, 0.4f * dB2);
                float dC = fmaf(0.6f, dC1, 0.4f * dC2);
                float dD = fmaf(0.6f, dD1, 0.4f * dD2);
                dA += __shfl_xor(dA, 1, 64);
                dA += __shfl_xor(dA, 2, 64);
                dA += __shfl_xor(dA, 4, 64);
                dB += __shfl_xor(dB, 1, 64);
                dB += __shfl_xor(dB, 2, 64);
                dB += __shfl_xor(dB, 4, 64);
                dC += __shfl_xor(dC, 1, 64);
                dC += __shfl_xor(dC, 2, 64);
                dC += __shfl_xor(dC, 4, 64);
                dD += __shfl_xor(dD, 1, 64);
                dD += __shfl_xor(dD, 2, 64);
                dD += __shfl_xor(dD, 4, 64);
                float eAv = (eA < nc) ? dA : -INFINITY;
                float eBv = (eB < nc) ? dB : -INFINITY;
                float eCv = (eC < nc) ? dC : -INFINITY;
                float eDv = (eD < nc) ? dD : -INFINITY;
                float M = fmaxf(fmaxf(eAv, eBv), fmaxf(eCv, eDv));
                M = fmaxf(M, __shfl_xor(M, 8, 64));
                M = fmaxf(M, __shfl_xor(M, 16, 64));
                M = fmaxf(M, __shfl_xor(M, 32, 64));
                if (M > m + 8.f) {                         // defer-max (T13)
                    float sc = __expf(m - M);
                    m = M;
                    ssum *= sc;
#pragma unroll
                    for (int q = 0; q < 4; ++q) acc2[q] *= sc;
                }
                float pA = __expf(eAv - m);
                float pB = __expf(eBv - m);
                float pC = __expf(eCv - m);
                float pD = __expf(eDv - m);
                ssum += (pA + pB) + (pC + pD);
#pragma unroll
                for (int q = 0; q < 4; ++q) {
                    acc2[q] += rA[q] * pA;
                    acc2[q] += rB[q] * pB;
                    acc2[q] += rC[q] * pC;
                    acc2[q] += rD[q] * pD;
                }
            }
        }
#pragma unroll
        for (int off = 8; off < 64; off <<= 1) {
            ssum += __shfl_xor(ssum, off, 64);
#pragma unroll
            for (int q = 0; q < 4; ++q) {
                acc2[q].x += __shfl_xor(acc2[q].x, off, 64);
                acc2[q].y += __shfl_xor(acc2[q].y, off, 64);
            }
        }
        float inv = 1.f / (ssum + EPS_F);
        if (g == 0) {
            float2* op = (float2*)&s_out[wid][f0];
#pragma unroll
            for (int q = 0; q < 2; ++q) {
                float2 v0, v1;
                v0.x = acc2[2 * q].x * inv;     v0.y = acc2[2 * q].y * inv;
                v1.x = acc2[2 * q + 1].x * inv; v1.y = acc2[2 * q + 1].y * inv;
                op[2 * q] = v0;
                op[2 * q + 1] = v1;
            }
        }
        // same-wave LDS handoff: no barrier needed
        out[(size_t)w * F_OUT + lane] = s_out[wid][lane] + san(bias[lane]);
    }
}

// ---------------- launch ------------------------------------------------------
extern "C" void kernel_launch(void* const* d_in, const int* in_sizes, int n_in,
                              void* d_out, int out_size, void* d_ws, size_t ws_size,
                              hipStream_t stream) {
    const float* x    = (const float*)d_in[0];
    const int*   ei   = (const int*)d_in[1];
    const float* Wl1  = (const float*)d_in[2];
    const float* Wr1  = (const float*)d_in[3];
    const float* att1 = (const float*)d_in[4];
    const float* b1   = (const float*)d_in[5];
    const float* Wl2  = (const float*)d_in[6];
    const float* Wr2  = (const float*)d_in[7];
    const float* att2 = (const float*)d_in[8];
    const float* b2   = (const float*)d_in[9];

    int E = in_sizes[1] / 2;
    const int* src = ei;
    const int* dst = ei + E;

    int gE = (E + 255) / 256;
    int gSA = (E + CH_E - 1) / CH_E;

    prep_hist<<<gE, 256, 0, stream>>>(dst, E, Wl1, Wr1, Wl2, Wr2);
    scanA<<<NPART, 256, 0, stream>>>();
    scanC2<<<NPART, 256, 0, stream>>>(E);
    sortA_gemm1<<<gSA + GEMM1_BLOCKS, 256, 0, stream>>>(src, dst, E, gSA, x);
    sortB<<<NBUCK, 256, 0, stream>>>();

    // ---- layer 1 ----
    att_agg1<<<ATT_GRID, 256, 0, stream>>>(att1, b1);

    // ---- layer 2 ----
    gemm2<<<MT, 256, 0, stream>>>();
    att_agg2<<<ATT_GRID, 256, 0, stream>>>(att2, b2, (float*)d_out);
}

// Round 12
// 335.988 us; speedup vs baseline: 1.1938x; 1.1885x over previous
//
#include <hip/hip_runtime.h>

#define N_NODES 50000
#define M_PAD 50048            // 391 * 128
#define MT 391
#define GEMM1_BLOCKS 782       // (2 N-blocks) x (391 M-blocks), N fastest
#define F_IN 256
#define F_H 128
#define F_OUT 64
#define NEG_SLOPE 0.2f
#define EPS_F 1e-16f
#define NBUCK 196              // coarse buckets: dst >> 8
#define CH_E 4096              // edges per sortA block -> 391 blocks
#define BUCKCAP 9216           // bucket slot: mean 8163 + 11.7 sigma
#define NQUAD 12500            // N_NODES / 4
#define ATT_GRID 2048          // persistent blocks
#define FUSED_LDS 40960        // max(gemm1 40KB, sortA ~24KB)

typedef __bf16 bf16x8 __attribute__((ext_vector_type(8)));
typedef float f32x4 __attribute__((ext_vector_type(4)));
typedef float f32x2 __attribute__((ext_vector_type(2)));

// ---------------- device-global scratch ------------------------------------
__device__ unsigned short g_B1h[256 * 256];
__device__ unsigned short g_B1l[256 * 256];
__device__ unsigned short g_B2h[128 * 128];
__device__ unsigned short g_B2l[128 * 128];
__device__ unsigned short g_hh[(size_t)M_PAD * F_H];
__device__ unsigned short g_hl[(size_t)M_PAD * F_H];
// gather tables: xl in bf16 (halves gather bytes), xr in f32 (read once/dst)
__device__ unsigned short g_xl1b[(size_t)N_NODES * F_H];
__device__ float g_xr1[(size_t)N_NODES * F_H];
__device__ unsigned short g_xl2b[(size_t)N_NODES * F_OUT];
__device__ float g_xr2[(size_t)N_NODES * F_OUT];
// slotted CSR (no histogram/scan: bucket b owns [b*BUCKCAP, (b+1)*BUCKCAP))
__device__ unsigned g_rowstart[N_NODES];
__device__ unsigned g_rowend[N_NODES];
__device__ unsigned g_bcursor[NBUCK];
__device__ unsigned g_bucketed[(size_t)NBUCK * BUCKCAP];   // src | dst<<16
__device__ int g_src_sorted[(size_t)NBUCK * BUCKCAP];

// ---------------- helpers ---------------------------------------------------
__device__ inline float san(float v) { return fminf(fmaxf(v, -64.f), 64.f); }
__device__ inline unsigned short f2bf(float f) {        // RNE f32->bf16
    unsigned u = __float_as_uint(f);
    return (unsigned short)((u + 0x7fffu + ((u >> 16) & 1u)) >> 16);
}
__device__ inline float bf2f(unsigned short h) {
    return __uint_as_float(((unsigned)h) << 16);
}
__device__ inline float blo(unsigned w) { return __uint_as_float(w << 16); }
__device__ inline float bhi(unsigned w) { return __uint_as_float(w & 0xffff0000u); }

// ---------------- prep: weight prepack + pad_h + bcursor init ---------------
// CSR hist/scans deleted: slotted buckets need only constant cursor init.
__global__ __launch_bounds__(256) void prep_w(const float* __restrict__ Wl1,
                                              const float* __restrict__ Wr1,
                                              const float* __restrict__ Wl2,
                                              const float* __restrict__ Wr2) {
    int i = blockIdx.x * 256 + threadIdx.x;
    if (i < 256 * 256) {                               // W1 prepack
        int n = i >> 8, k = i & 255;
        float v = san((n < 128) ? Wl1[k * 128 + n] : Wr1[k * 128 + (n - 128)]);
        unsigned short h = f2bf(v);
        g_B1h[n * 256 + k] = h;
        g_B1l[n * 256 + k] = f2bf(v - bf2f(h));
    }
    if (i < 128 * 128) {                               // W2 prepack
        int n = i >> 7, k = i & 127;
        float v = san((n < 64) ? Wl2[k * 64 + n] : Wr2[k * 64 + (n - 64)]);
        unsigned short h = f2bf(v);
        g_B2h[n * 128 + k] = h;
        g_B2l[n * 128 + k] = f2bf(v - bf2f(h));
    }
    if (i < (M_PAD - N_NODES) * F_H) {                 // pad_h
        g_hh[(size_t)N_NODES * F_H + i] = 0;
        g_hl[(size_t)N_NODES * F_H + i] = 0;
    }
    if (i < NBUCK) g_bcursor[i] = (unsigned)i * BUCKCAP;   // slot cursors
}

// ---------------- fused sortA + gemm1 (same dependency level) ---------------
// sortA blocks (latency-bound) co-reside with gemm1's MFMA-heavy blocks.
// gemm1: 128x128 tile, (2 N) x (391 M), N fastest — best measured shape
// (rounds 8/10 showed retiles are neutral-to-worse: staging-slot bound).
__global__ __launch_bounds__(256) void sortA_gemm1(const int* __restrict__ src,
                                                   const int* __restrict__ dst,
                                                   int E, int nSort,
                                                   const float* __restrict__ x) {
    __shared__ __align__(16) unsigned char s_raw[FUSED_LDS];
    int t = threadIdx.x;

    if ((int)blockIdx.x < nSort) {
        // ================= sortA body (block-local LDS counting sort) ======
        unsigned* l_cnt  = (unsigned*)s_raw;                 // NBUCK
        unsigned* l_base = l_cnt + NBUCK;                    // NBUCK
        int*      l_gadj = (int*)(l_base + NBUCK);           // NBUCK
        unsigned* sc     = (unsigned*)(l_gadj + NBUCK);      // 256
        unsigned* stageW = sc + 256;                         // CH_E words
        unsigned char* stageB = (unsigned char*)(stageW + CH_E); // CH_E bytes
        int e0 = blockIdx.x * CH_E;
        int e1 = min(e0 + CH_E, E);
        int n = e1 - e0;
        for (int i = t; i < NBUCK; i += 256) l_cnt[i] = 0u;
        __syncthreads();
        for (int e = e0 + t; e < e1; e += 256)
            atomicAdd(&l_cnt[dst[e] >> 8], 1u);
        __syncthreads();
        {   // exclusive prefix of l_cnt -> l_base
            unsigned v = (t < NBUCK) ? l_cnt[t] : 0u;
            sc[t] = v;
            __syncthreads();
            for (int off = 1; off < 256; off <<= 1) {
                unsigned u = (t >= off) ? sc[t - off] : 0u;
                __syncthreads();
                sc[t] += u;
                __syncthreads();
            }
            if (t < NBUCK) l_base[t] = sc[t] - v;
        }
        __syncthreads();
        for (int b = t; b < NBUCK; b += 256) {   // claim runs in bucket slots
            unsigned c = l_cnt[b];
            unsigned gb = c ? atomicAdd(&g_bcursor[b], c) : 0u;
            l_gadj[b] = (int)gb - (int)l_base[b];
            l_cnt[b] = l_base[b];                // becomes local cursor
        }
        __syncthreads();
        for (int e = e0 + t; e < e1; e += 256) { // scatter into LDS stage
            int d = dst[e];
            int b = d >> 8;
            unsigned p = atomicAdd(&l_cnt[b], 1u);
            stageW[p] = (unsigned)src[e] | ((unsigned)d << 16);
            stageB[p] = (unsigned char)b;
        }
        __syncthreads();
        for (int i = t; i < n; i += 256) {       // linear copy out
            int b = stageB[i];
            g_bucketed[l_gadj[b] + i] = stageW[i];
        }
        return;
    }

    // ================= gemm1 body (128x128, N fastest) =====================
    typedef unsigned short row40[40];
    row40* As_h = (row40*)s_raw;                       // 128 rows
    row40* As_l = (row40*)(s_raw + 10240);
    row40* Bs_h = (row40*)(s_raw + 20480);
    row40* Bs_l = (row40*)(s_raw + 30720);

    int bx = blockIdx.x - nSort;              // 0..781
    const int n0 = (bx & 1) * 128;            // N fastest (A-tile L2 sharing)
    const int m0 = (bx >> 1) * 128;
    const int wave = t >> 6, lane = t & 63;
    const int wm = (wave >> 1) * 64, wn = (wave & 1) * 64;
    const int lr = lane & 15, g8 = (lane >> 4) * 8;
    const int srow = t >> 1, shalf = (t & 1) * 16;

    f32x4 acc[4][4];
#pragma unroll
    for (int i = 0; i < 4; ++i)
#pragma unroll
        for (int j = 0; j < 4; ++j) acc[i][j] = (f32x4){0.f, 0.f, 0.f, 0.f};

    for (int kb = 0; kb < 256; kb += 32) {
        __syncthreads();
        {   // A stage: f32 -> (hi,lo) bf16 in-flight (bit-identical split)
            int grow = m0 + srow;
            float f[16];
            if (grow < N_NODES) {
                const float4* xp = (const float4*)(x + (size_t)grow * F_IN + kb + shalf);
                float4 v0 = xp[0], v1 = xp[1], v2 = xp[2], v3 = xp[3];
                f[0] = v0.x;  f[1] = v0.y;  f[2] = v0.z;  f[3] = v0.w;
                f[4] = v1.x;  f[5] = v1.y;  f[6] = v1.z;  f[7] = v1.w;
                f[8] = v2.x;  f[9] = v2.y;  f[10] = v2.z; f[11] = v2.w;
                f[12] = v3.x; f[13] = v3.y; f[14] = v3.z; f[15] = v3.w;
            } else {
#pragma unroll
                for (int j = 0; j < 16; ++j) f[j] = 0.f;
            }
            unsigned hw[8], lw[8];
#pragma unroll
            for (int j = 0; j < 8; ++j) {
                float a = san(f[2 * j]), b = san(f[2 * j + 1]);
                unsigned short ha = f2bf(a), hb = f2bf(b);
                unsigned short la = f2bf(a - bf2f(ha)), lb = f2bf(b - bf2f(hb));
                hw[j] = ((unsigned)hb << 16) | ha;
                lw[j] = ((unsigned)lb << 16) | la;
            }
            *(uint4*)&As_h[srow][shalf]     = make_uint4(hw[0], hw[1], hw[2], hw[3]);
            *(uint4*)&As_h[srow][shalf + 8] = make_uint4(hw[4], hw[5], hw[6], hw[7]);
            *(uint4*)&As_l[srow][shalf]     = make_uint4(lw[0], lw[1], lw[2], lw[3]);
            *(uint4*)&As_l[srow][shalf + 8] = make_uint4(lw[4], lw[5], lw[6], lw[7]);
        }
        {
            size_t gb = (size_t)(n0 + srow) * 256 + kb + shalf;
            *(uint4*)&Bs_h[srow][shalf]     = *(const uint4*)(g_B1h + gb);
            *(uint4*)&Bs_h[srow][shalf + 8] = *(const uint4*)(g_B1h + gb + 8);
            *(uint4*)&Bs_l[srow][shalf]     = *(const uint4*)(g_B1l + gb);
            *(uint4*)&Bs_l[srow][shalf + 8] = *(const uint4*)(g_B1l + gb + 8);
        }
        __syncthreads();

        bf16x8 af_h[4], af_l[4], bf_h[4], bf_l[4];
#pragma unroll
        for (int i = 0; i < 4; ++i) {
            af_h[i] = *(const bf16x8*)&As_h[wm + i * 16 + lr][g8];
            af_l[i] = *(const bf16x8*)&As_l[wm + i * 16 + lr][g8];
        }
#pragma unroll
        for (int j = 0; j < 4; ++j) {
            bf_h[j] = *(const bf16x8*)&Bs_h[wn + j * 16 + lr][g8];
            bf_l[j] = *(const bf16x8*)&Bs_l[wn + j * 16 + lr][g8];
        }
#pragma unroll
        for (int i = 0; i < 4; ++i)
#pragma unroll
            for (int j = 0; j < 4; ++j) {
                acc[i][j] = __builtin_amdgcn_mfma_f32_16x16x32_bf16(af_h[i], bf_h[j], acc[i][j], 0, 0, 0);
                acc[i][j] = __builtin_amdgcn_mfma_f32_16x16x32_bf16(af_h[i], bf_l[j], acc[i][j], 0, 0, 0);
                acc[i][j] = __builtin_amdgcn_mfma_f32_16x16x32_bf16(af_l[i], bf_h[j], acc[i][j], 0, 0, 0);
            }
    }

    const int drow = (lane >> 4) * 4;
#pragma unroll
    for (int i = 0; i < 4; ++i)
#pragma unroll
        for (int j = 0; j < 4; ++j) {
            int gn = n0 + wn + j * 16 + lr;
#pragma unroll
            for (int r = 0; r < 4; ++r) {
                int m = m0 + wm + i * 16 + drow + r;
                if (m < N_NODES) {
                    if (gn < F_H) g_xl1b[(size_t)m * F_H + gn] = f2bf(acc[i][j][r]);
                    else          g_xr1[(size_t)m * F_H + (gn - F_H)] = acc[i][j][r];
                }
            }
        }
}

// ---------------- sortB: per-node count+prefix (builds rowstart) + scatter --
__global__ __launch_bounds__(256) void sortB() {
    __shared__ unsigned l_cnt[256];
    __shared__ unsigned l_sc[256];
    int b = blockIdx.x;
    int d0 = b * 256;
    int t = threadIdx.x;
    unsigned bstart = (unsigned)b * BUCKCAP;
    unsigned count = g_bcursor[b] - bstart;
    l_cnt[t] = 0u;
    __syncthreads();
    for (unsigned i = t; i < count; i += 256) {     // pass 1: per-node counts
        unsigned e = g_bucketed[bstart + i];
        atomicAdd(&l_cnt[(e >> 16) - d0], 1u);
    }
    __syncthreads();
    unsigned v = l_cnt[t];
    l_sc[t] = v;
    __syncthreads();
    for (int off = 1; off < 256; off <<= 1) {       // block prefix
        unsigned u = (t >= off) ? l_sc[t - off] : 0u;
        __syncthreads();
        l_sc[t] += u;
        __syncthreads();
    }
    unsigned rs = bstart + l_sc[t] - v;             // exclusive, slotted
    int node = d0 + t;
    if (node < N_NODES) {
        g_rowstart[node] = rs;
        g_rowend[node] = rs + v;
    }
    l_cnt[t] = rs;                                   // becomes cursor
    __syncthreads();
    for (unsigned i = t; i < count; i += 256) {     // pass 2: scatter
        unsigned e = g_bucketed[bstart + i];
        unsigned d = e >> 16;
        unsigned pos = atomicAdd(&l_cnt[d - d0], 1u);
        g_src_sorted[pos] = (int)(e & 0xFFFFu);
    }
}

// ---------------- gemm2: 128x128 tile (A read once) -------------------------
__global__ __launch_bounds__(256) void gemm2() {
    __shared__ __align__(16) unsigned short As_h[128][40];
    __shared__ __align__(16) unsigned short As_l[128][40];
    __shared__ __align__(16) unsigned short Bs_h[128][40];
    __shared__ __align__(16) unsigned short Bs_l[128][40];

    const int m0 = blockIdx.x * 128;
    const int t = threadIdx.x;
    const int wave = t >> 6, lane = t & 63;
    const int wm = (wave >> 1) * 64, wn = (wave & 1) * 64;
    const int lr = lane & 15, g8 = (lane >> 4) * 8;
    const int srow = t >> 1, shalf = (t & 1) * 16;

    f32x4 acc[4][4];
#pragma unroll
    for (int i = 0; i < 4; ++i)
#pragma unroll
        for (int j = 0; j < 4; ++j) acc[i][j] = (f32x4){0.f, 0.f, 0.f, 0.f};

    for (int kb = 0; kb < 128; kb += 32) {
        __syncthreads();
        {
            size_t ga = (size_t)(m0 + srow) * 128 + kb + shalf;
            *(uint4*)&As_h[srow][shalf]     = *(const uint4*)(g_hh + ga);
            *(uint4*)&As_h[srow][shalf + 8] = *(const uint4*)(g_hh + ga + 8);
            *(uint4*)&As_l[srow][shalf]     = *(const uint4*)(g_hl + ga);
            *(uint4*)&As_l[srow][shalf + 8] = *(const uint4*)(g_hl + ga + 8);
            size_t gb = (size_t)srow * 128 + kb + shalf;
            *(uint4*)&Bs_h[srow][shalf]     = *(const uint4*)(g_B2h + gb);
            *(uint4*)&Bs_h[srow][shalf + 8] = *(const uint4*)(g_B2h + gb + 8);
            *(uint4*)&Bs_l[srow][shalf]     = *(const uint4*)(g_B2l + gb);
            *(uint4*)&Bs_l[srow][shalf + 8] = *(const uint4*)(g_B2l + gb + 8);
        }
        __syncthreads();

        bf16x8 af_h[4], af_l[4], bf_h[4], bf_l[4];
#pragma unroll
        for (int i = 0; i < 4; ++i) {
            af_h[i] = *(const bf16x8*)&As_h[wm + i * 16 + lr][g8];
            af_l[i] = *(const bf16x8*)&As_l[wm + i * 16 + lr][g8];
        }
#pragma unroll
        for (int j = 0; j < 4; ++j) {
            bf_h[j] = *(const bf16x8*)&Bs_h[wn + j * 16 + lr][g8];
            bf_l[j] = *(const bf16x8*)&Bs_l[wn + j * 16 + lr][g8];
        }
#pragma unroll
        for (int i = 0; i < 4; ++i)
#pragma unroll
            for (int j = 0; j < 4; ++j) {
                acc[i][j] = __builtin_amdgcn_mfma_f32_16x16x32_bf16(af_h[i], bf_h[j], acc[i][j], 0, 0, 0);
                acc[i][j] = __builtin_amdgcn_mfma_f32_16x16x32_bf16(af_h[i], bf_l[j], acc[i][j], 0, 0, 0);
                acc[i][j] = __builtin_amdgcn_mfma_f32_16x16x32_bf16(af_l[i], bf_h[j], acc[i][j], 0, 0, 0);
            }
    }

    const int drow = (lane >> 4) * 4;
#pragma unroll
    for (int i = 0; i < 4; ++i)
#pragma unroll
        for (int j = 0; j < 4; ++j) {
            int gn = wn + j * 16 + lr;
#pragma unroll
            for (int r = 0; r < 4; ++r) {
                int m = m0 + wm + i * 16 + drow + r;
                if (m < N_NODES) {
                    if (gn < F_OUT) g_xl2b[(size_t)m * F_OUT + gn] = f2bf(acc[i][j][r]);
                    else            g_xr2[(size_t)m * F_OUT + (gn - F_OUT)] = acc[i][j][r];
                }
            }
        }
}

// ---------------- fused attention+aggregate, layer 1 ------------------------
// unroll-2 octet batching + barrier-free same-wave LDS handoff.
// At the L2<->L3 fabric floor (~86us, FETCH 226MB @ ~3.0 TB/s).
__global__ __launch_bounds__(256) void att_agg1(const float* __restrict__ att,
                                                const float* __restrict__ bias) {
    __shared__ float s_out[4][F_H];
    int wid = threadIdx.x >> 6, lane = threadIdx.x & 63;
    int g = lane >> 3;
    int fi = lane & 7;
    int f0 = fi * 16;

    f32x2 at2[8];
    {
        const float4* atp = (const float4*)(att + f0);
#pragma unroll
        for (int q = 0; q < 4; ++q) {
            float4 a = atp[q];
            at2[2 * q]     = (f32x2){san(a.x), san(a.y)};
            at2[2 * q + 1] = (f32x2){san(a.z), san(a.w)};
        }
    }

    for (int qd = blockIdx.x; qd < NQUAD; qd += gridDim.x) {
        int w = qd * 4 + wid;

        f32x2 xr2[8];
        {
            const float4* xrp = (const float4*)(g_xr1 + (size_t)w * F_H + f0);
#pragma unroll
            for (int q = 0; q < 4; ++q) {
                float4 v = xrp[q];
                xr2[2 * q]     = (f32x2){v.x, v.y};
                xr2[2 * q + 1] = (f32x2){v.z, v.w};
            }
        }

        int beg = (int)g_rowstart[w], end = (int)g_rowend[w];
        float m = -INFINITY, ssum = 0.f;
        f32x2 acc2[8];
#pragma unroll
        for (int q = 0; q < 8; ++q) acc2[q] = (f32x2){0.f, 0.f};

        for (int c0 = beg; c0 < end; c0 += 64) {
            int nc = min(64, end - c0);
            int mysrc = (lane < nc) ? g_src_sorted[c0 + lane] : 0;
            for (int r0 = 0; r0 < nc; r0 += 16) {
                int eA = r0 + g, eB = r0 + 8 + g;          // eB <= 63 always
                int sA = __shfl(mysrc, eA, 64);
                int sB = __shfl(mysrc, eB, 64);
                const uint4* rpA = (const uint4*)(g_xl1b + (size_t)sA * F_H + f0);
                const uint4* rpB = (const uint4*)(g_xl1b + (size_t)sB * F_H + f0);
                uint4 a0 = rpA[0], a1 = rpA[1];
                uint4 b0 = rpB[0], b1 = rpB[1];
                f32x2 rA[8];
                rA[0] = (f32x2){blo(a0.x), bhi(a0.x)};
                rA[1] = (f32x2){blo(a0.y), bhi(a0.y)};
                rA[2] = (f32x2){blo(a0.z), bhi(a0.z)};
                rA[3] = (f32x2){blo(a0.w), bhi(a0.w)};
                rA[4] = (f32x2){blo(a1.x), bhi(a1.x)};
                rA[5] = (f32x2){blo(a1.y), bhi(a1.y)};
                rA[6] = (f32x2){blo(a1.z), bhi(a1.z)};
                rA[7] = (f32x2){blo(a1.w), bhi(a1.w)};
                float dA1 = 0.f, dA2 = 0.f;
#pragma unroll
                for (int q = 0; q < 8; ++q) {
                    f32x2 z = rA[q] + xr2[q];
                    dA1 = fmaf(z.x, at2[q].x, dA1);
                    dA2 = fmaf(fabsf(z.x), at2[q].x, dA2);
                    dA1 = fmaf(z.y, at2[q].y, dA1);
                    dA2 = fmaf(fabsf(z.y), at2[q].y, dA2);
                }
                float dA = fmaf(0.6f, dA1, 0.4f * dA2);
                f32x2 rB[8];
                rB[0] = (f32x2){blo(b0.x), bhi(b0.x)};
                rB[1] = (f32x2){blo(b0.y), bhi(b0.y)};
                rB[2] = (f32x2){blo(b0.z), bhi(b0.z)};
                rB[3] = (f32x2){blo(b0.w), bhi(b0.w)};
                rB[4] = (f32x2){blo(b1.x), bhi(b1.x)};
                rB[5] = (f32x2){blo(b1.y), bhi(b1.y)};
                rB[6] = (f32x2){blo(b1.z), bhi(b1.z)};
                rB[7] = (f32x2){blo(b1.w), bhi(b1.w)};
                float dB1 = 0.f, dB2 = 0.f;
#pragma unroll
                for (int q = 0; q < 8; ++q) {
                    f32x2 z = rB[q] + xr2[q];
                    dB1 = fmaf(z.x, at2[q].x, dB1);
                    dB2 = fmaf(fabsf(z.x), at2[q].x, dB2);
                    dB1 = fmaf(z.y, at2[q].y, dB1);
                    dB2 = fmaf(fabsf(z.y), at2[q].y, dB2);
                }
                float dB = fmaf(0.6f, dB1, 0.4f * dB2);
                dA += __shfl_xor(dA, 1, 64);
                dA += __shfl_xor(dA, 2, 64);
                dA += __shfl_xor(dA, 4, 64);
                dB += __shfl_xor(dB, 1, 64);
                dB += __shfl_xor(dB, 2, 64);
                dB += __shfl_xor(dB, 4, 64);
                float eAv = (eA < nc) ? dA : -INFINITY;
                float eBv = (eB < nc) ? dB : -INFINITY;
                float M = fmaxf(eAv, eBv);
                M = fmaxf(M, __shfl_xor(M, 8, 64));
                M = fmaxf(M, __shfl_xor(M, 16, 64));
                M = fmaxf(M, __shfl_xor(M, 32, 64));
                if (M > m + 8.f) {                         // defer-max (T13)
                    float sc = __expf(m - M);              // 0 on first round
                    m = M;
                    ssum *= sc;
#pragma unroll
                    for (int q = 0; q < 8; ++q) acc2[q] *= sc;
                }
                float pA = __expf(eAv - m);                // 0 for invalid
                float pB = __expf(eBv - m);
                ssum += pA + pB;
#pragma unroll
                for (int q = 0; q < 8; ++q) {
                    acc2[q] += rA[q] * pA;
                    acc2[q] += rB[q] * pB;
                }
            }
        }
#pragma unroll
        for (int off = 8; off < 64; off <<= 1) {
            ssum += __shfl_xor(ssum, off, 64);
#pragma unroll
            for (int q = 0; q < 8; ++q) {
                acc2[q].x += __shfl_xor(acc2[q].x, off, 64);
                acc2[q].y += __shfl_xor(acc2[q].y, off, 64);
            }
        }
        float inv = 1.f / (ssum + EPS_F);
        if (g == 0) {
            float2* op = (float2*)&s_out[wid][f0];
#pragma unroll
            for (int q = 0; q < 8; ++q) {
                float2 v;
                v.x = acc2[q].x * inv; v.y = acc2[q].y * inv;
                op[q] = v;
            }
        }
        // same-wave LDS handoff: no barrier needed (per-wave DS ordering)
        int f2 = lane * 2;
        float2 o = *(float2*)&s_out[wid][f2];
        o.x = fmaxf(o.x + san(bias[f2]), 0.f);
        o.y = fmaxf(o.y + san(bias[f2 + 1]), 0.f);
        unsigned short hx = f2bf(o.x), hy = f2bf(o.y);
        unsigned short lx = f2bf(o.x - bf2f(hx)), ly = f2bf(o.y - bf2f(hy));
        size_t base = (size_t)w * F_H + f2;
        *(unsigned*)(g_hh + base) = ((unsigned)hy << 16) | hx;
        *(unsigned*)(g_hl + base) = ((unsigned)ly << 16) | lx;
    }
}

// ---------------- fused attention+aggregate, layer 2 (F=64) -----------------
// unroll-2 (R11 A/B: unroll-4 neutral -> keep the simpler form).
__global__ __launch_bounds__(256) void att_agg2(const float* __restrict__ att,
                                                const float* __restrict__ bias,
                                                float* __restrict__ out) {
    __shared__ float s_out[4][F_OUT];
    int wid = threadIdx.x >> 6, lane = threadIdx.x & 63;
    int g = lane >> 3;
    int fi = lane & 7;
    int f0 = fi * 8;

    f32x2 at2[4];
    {
        const float4* atp = (const float4*)(att + f0);
#pragma unroll
        for (int q = 0; q < 2; ++q) {
            float4 a = atp[q];
            at2[2 * q]     = (f32x2){san(a.x), san(a.y)};
            at2[2 * q + 1] = (f32x2){san(a.z), san(a.w)};
        }
    }

    for (int qd = blockIdx.x; qd < NQUAD; qd += gridDim.x) {
        int w = qd * 4 + wid;

        f32x2 xr2[4];
        {
            const float4* xrp = (const float4*)(g_xr2 + (size_t)w * F_OUT + f0);
#pragma unroll
            for (int q = 0; q < 2; ++q) {
                float4 v = xrp[q];
                xr2[2 * q]     = (f32x2){v.x, v.y};
                xr2[2 * q + 1] = (f32x2){v.z, v.w};
            }
        }

        int beg = (int)g_rowstart[w], end = (int)g_rowend[w];
        float m = -INFINITY, ssum = 0.f;
        f32x2 acc2[4];
#pragma unroll
        for (int q = 0; q < 4; ++q) acc2[q] = (f32x2){0.f, 0.f};

        for (int c0 = beg; c0 < end; c0 += 64) {
            int nc = min(64, end - c0);
            int mysrc = (lane < nc) ? g_src_sorted[c0 + lane] : 0;
            for (int r0 = 0; r0 < nc; r0 += 16) {
                int eA = r0 + g, eB = r0 + 8 + g;
                int sA = __shfl(mysrc, eA, 64);
                int sB = __shfl(mysrc, eB, 64);
                uint4 a0 = *(const uint4*)(g_xl2b + (size_t)sA * F_OUT + f0);
                uint4 b0 = *(const uint4*)(g_xl2b + (size_t)sB * F_OUT + f0);
                f32x2 rA[4], rB[4];
                rA[0] = (f32x2){blo(a0.x), bhi(a0.x)};
                rA[1] = (f32x2){blo(a0.y), bhi(a0.y)};
                rA[2] = (f32x2){blo(a0.z), bhi(a0.z)};
                rA[3] = (f32x2){blo(a0.w), bhi(a0.w)};
                rB[0] = (f32x2){blo(b0.x), bhi(b0.x)};
                rB[1] = (f32x2){blo(b0.y), bhi(b0.y)};
                rB[2] = (f32x2){blo(b0.z), bhi(b0.z)};
                rB[3] = (f32x2){blo(b0.w), bhi(b0.w)};
                float dA1 = 0.f, dA2 = 0.f, dB1 = 0.f, dB2 = 0.f;
#pragma unroll
                for (int q = 0; q < 4; ++q) {
                    f32x2 zA = rA[q] + xr2[q];
                    dA1 = fmaf(zA.x, at2[q].x, dA1);
                    dA2 = fmaf(fabsf(zA.x), at2[q].x, dA2);
                    dA1 = fmaf(zA.y, at2[q].y, dA1);
                    dA2 = fmaf(fabsf(zA.y), at2[q].y, dA2);
                    f32x2 zB = rB[q] + xr2[q];
                    dB1 = fmaf(zB.x, at2[q].x, dB1);
                    dB2 = fmaf(fabsf(zB.x), at2[q].x, dB2);
                    dB1 = fmaf(zB.y, at2[q].y, dB1);
                    dB2 = fmaf(fabsf(zB.y), at2[q].y, dB2);
                }
                float dA = fmaf(0.6f, dA1, 0.4f * dA2);
                float dB = fmaf(0.6f, dB1, 0.4f * dB2);
                dA += __shfl_xor(dA, 1, 64);
                dA += __shfl_xor(dA, 2, 64);
                dA += __shfl_xor(dA, 4, 64);
                dB += __shfl_xor(dB, 1, 64);
                dB += __shfl_xor(dB, 2, 64);
                dB += __shfl_xor(dB, 4, 64);
                float eAv = (eA < nc) ? dA : -INFINITY;
                float eBv = (eB < nc) ? dB : -INFINITY;
                float M = fmaxf(eAv, eBv);
                M = fmaxf(M, __shfl_xor(M, 8, 64));
                M = fmaxf(M, __shfl_xor(M, 16, 64));
                M = fmaxf(M, __shfl_xor(M, 32, 64));
                if (M > m + 8.f) {                         // defer-max (T13)
                    float sc = __expf(m - M);
                    m = M;
                    ssum *= sc;
#pragma unroll
                    for (int q = 0; q < 4; ++q) acc2[q] *= sc;
                }
                float pA = __expf(eAv - m);
                float pB = __expf(eBv - m);
                ssum += pA + pB;
#pragma unroll
                for (int q = 0; q < 4; ++q) {
                    acc2[q] += rA[q] * pA;
                    acc2[q] += rB[q] * pB;
                }
            }
        }
#pragma unroll
        for (int off = 8; off < 64; off <<= 1) {
            ssum += __shfl_xor(ssum, off, 64);
#pragma unroll
            for (int q = 0; q < 4; ++q) {
                acc2[q].x += __shfl_xor(acc2[q].x, off, 64);
                acc2[q].y += __shfl_xor(acc2[q].y, off, 64);
            }
        }
        float inv = 1.f / (ssum + EPS_F);
        if (g == 0) {
            float2* op = (float2*)&s_out[wid][f0];
#pragma unroll
            for (int q = 0; q < 2; ++q) {
                float2 v0, v1;
                v0.x = acc2[2 * q].x * inv;     v0.y = acc2[2 * q].y * inv;
                v1.x = acc2[2 * q + 1].x * inv; v1.y = acc2[2 * q + 1].y * inv;
                op[2 * q] = v0;
                op[2 * q + 1] = v1;
            }
        }
        // same-wave LDS handoff: no barrier needed
        out[(size_t)w * F_OUT + lane] = s_out[wid][lane] + san(bias[lane]);
    }
}

// ---------------- launch ------------------------------------------------------
extern "C" void kernel_launch(void* const* d_in, const int* in_sizes, int n_in,
                              void* d_out, int out_size, void* d_ws, size_t ws_size,
                              hipStream_t stream) {
    const float* x    = (const float*)d_in[0];
    const int*   ei   = (const int*)d_in[1];
    const float* Wl1  = (const float*)d_in[2];
    const float* Wr1  = (const float*)d_in[3];
    const float* att1 = (const float*)d_in[4];
    const float* b1   = (const float*)d_in[5];
    const float* Wl2  = (const float*)d_in[6];
    const float* Wr2  = (const float*)d_in[7];
    const float* att2 = (const float*)d_in[8];
    const float* b2   = (const float*)d_in[9];

    int E = in_sizes[1] / 2;
    const int* src = ei;
    const int* dst = ei + E;

    int gSA = (E + CH_E - 1) / CH_E;

    prep_w<<<256, 256, 0, stream>>>(Wl1, Wr1, Wl2, Wr2);
    sortA_gemm1<<<gSA + GEMM1_BLOCKS, 256, 0, stream>>>(src, dst, E, gSA, x);
    sortB<<<NBUCK, 256, 0, stream>>>();

    // ---- layer 1 ----
    att_agg1<<<ATT_GRID, 256, 0, stream>>>(att1, b1);

    // ---- layer 2 ----
    gemm2<<<MT, 256, 0, stream>>>();
    att_agg2<<<ATT_GRID, 256, 0, stream>>>(att2, b2, (float*)d_out);
}